// Round 3
// baseline (1090.352 us; speedup 1.0000x reference)
//
#include <hip/hip_runtime.h>
#include <math.h>

#define MAXNORM_F 0.996f

typedef __attribute__((ext_vector_type(8))) short bf16x8;
typedef __attribute__((ext_vector_type(4))) float f32x4;

__device__ __forceinline__ short f2bf(float f) {
    union { float f; unsigned u; } v; v.f = f;
    unsigned r = v.u + 0x7FFF + ((v.u >> 16) & 1);
    return (short)(r >> 16);
}
__device__ __forceinline__ float bf2f(short s) {
    union { unsigned u; float f; } v; v.u = ((unsigned)(unsigned short)s) << 16;
    return v.f;
}

__device__ __forceinline__ float artanh_c(float x) {
    const float lim = 1.0f - 1e-5f;
    x = fminf(fmaxf(x, -lim), lim);
    return 0.5f * logf((1.0f + x) / (1.0f - x));
}

// full 64-lane wave sum, result in all lanes
__device__ __forceinline__ float wsum(float v) {
#pragma unroll
    for (int m = 32; m > 0; m >>= 1) v += __shfl_xor(v, m, 64);
    return v;
}

// ---- weight pack: fp32 [K][N] -> bf16 [ntile][kb][seg(2:hi,lo)][kg(4)][n(128)][j(8)] ----
__global__ __launch_bounds__(256) void pack_w_kernel(
    const float* __restrict__ W, int Kreal, int KB, int N, short* __restrict__ out) {
    int e = blockIdx.x * 256 + threadIdx.x;
    int total = (N >> 7) * KB * 2 * 4096;
    if (e >= total) return;
    int j   = e & 7;
    int n   = (e >> 3) & 127;
    int kg  = (e >> 10) & 3;
    int seg = (e >> 12) & 1;
    int rest = e >> 13;
    int kb  = rest % KB;
    int nt  = rest / KB;
    int k = (kb << 5) + (kg << 3) + j;
    int col = (nt << 7) + n;
    float v = (k < Kreal) ? W[(size_t)k * N + col] : 0.f;
    short hi = f2bf(v);
    out[e] = (seg == 0) ? hi : f2bf(v - bf2f(hi));
}

// ---- prep: zscore + concat + expmap0 -> bf16, interleaved [kb][hi32|lo32]. Wave-per-row. ----
__global__ __launch_bounds__(256) void prep_kernel(
    const float* __restrict__ s0, const float* __restrict__ s1,
    const float* __restrict__ s2, const float* __restrict__ s3,
    int f0, int f1, int f2, int f3,
    short* __restrict__ Xb, float* __restrict__ xn_out) {
    __shared__ float xbuf[4][1712];
    const int lane = threadIdx.x & 63, wave = threadIdx.x >> 6;
    const int row = blockIdx.x * 4 + wave;
    float* xb = xbuf[wave];
    const float* srcs[4] = {s0, s1, s2, s3};
    const int fs[4] = {f0, f1, f2, f3};
    int off = 0;
    for (int b = 0; b < 4; b++) {
        int F = fs[b];
        if (F == 0) break;
        const float* srow = srcs[b] + (size_t)row * F;
        float ps = 0.f;
        for (int i = lane; i < F; i += 64) { float v = srow[i]; xb[off + i] = v; ps += v; }
        float mean = wsum(ps) / (float)F;
        float pq = 0.f;
        for (int i = lane; i < F; i += 64) { float d = xb[off + i] - mean; pq += d * d; }
        float var = wsum(pq) / (float)(F - 1);
        float inv = 1.0f / (sqrtf(var) + 1e-8f);
        for (int i = lane; i < F; i += 64) xb[off + i] = (xb[off + i] - mean) * inv;
        off += F;
    }
    float pn = 0.f;
    for (int i = lane; i < 1711; i += 64) pn += xb[i] * xb[i];
    float n = fmaxf(sqrtf(wsum(pn)), 1e-15f);
    float t = tanhf(n);
    float sc = t / n;
    short* xrow = Xb + (size_t)row * 3456;   // [kb(54)][hi(32)|lo(32)]
    for (int i = lane; i < 1728; i += 64) {
        float v = (i < 1711) ? sc * xb[i] : 0.f;
        short hi = f2bf(v);
        int base = (i >> 5) * 64 + (i & 31);
        xrow[base] = hi;
        xrow[base + 32] = f2bf(v - bf2f(hi));
    }
    if (lane == 0) xn_out[row] = fmaxf(t, 1e-15f);
}

// ---- bf16 MFMA GEMM, fused 3-term split precision, line-dense A, XCD swizzle ----
// A: bf16 [M][lda], lda = 2*Kpad, layout [kb][hi32|lo32] per row (128B lines).
// Wp packed per pack_w_kernel. Grid: 1D, NT*M/128 blocks, NT = 1<<ntShift.
// BK=64 double-buffered: each iteration stages TWO kb (32KB A + 32KB B) into
// the spare buffer while running 2x48 MFMAs from the current one; one barrier
// per 64 K-elements. LDS 128KB -> 1 block/CU; the doubled MFMA window per
// barrier covers the vmcnt(0) drain that capped the BK=32 version at ~57%.
// Requires KB even (54/32/16 all are).
__global__ __launch_bounds__(256) void gemm_mfma(
    const short* __restrict__ A, int lda, int KB,
    const short* __restrict__ Wp,
    float* __restrict__ C, int N, int ntShift) {
    __shared__ short As[2][16384];  // [buf][h(2)][128 rows x 64 shorts], 16B-unit slot = p ^ (row&7)
    __shared__ short Bs[2][16384];  // [buf][h(2)][seg(2)][kg(4)][n(128)][j(8)]
    const int tid = threadIdx.x;
    const int lane = tid & 63;
    const int wave = __builtin_amdgcn_readfirstlane(tid >> 6);
    const int waveM = wave >> 1, waveN = wave & 1;
    const int kg = lane >> 4, l16 = lane & 15;

    // XCD-aware swizzle: same m-strip -> same XCD, consecutive in time
    int flat = blockIdx.x;
    int xcd = flat & 7;
    int idx = flat >> 3;
    int q = idx >> ntShift;
    int nt = idx & ((1 << ntShift) - 1);
    int mt = q * 8 + xcd;
    const int m0 = mt * 128;

    f32x4 acc[4][4] = {};
    const short* Bbase = Wp + (size_t)nt * KB * 8192;
    const int KB2 = KB >> 1;

    // stage K-step t (= kb 2t, 2t+1) into buffer b. LDS dest is wave-uniform
    // base (+lane*16B implicit); the A swizzle (unit slot p = (u&7)^(row&7))
    // lives in the per-lane GLOBAL address (pre-swizzled-source pattern).
    auto stage = [&](int b, int t) {
#pragma unroll
        for (int h = 0; h < 2; h++) {
            int kb = 2 * t + h;
#pragma unroll
            for (int c = 0; c < 4; c++) {
                int u = c * 256 + wave * 64 + lane;
                int row = u >> 3;
                int p = (u & 7) ^ (row & 7);
                const short* ga = A + (size_t)(m0 + row) * lda + kb * 64 + p * 8;
                __builtin_amdgcn_global_load_lds(
                    (const __attribute__((address_space(1))) unsigned int*)ga,
                    (__attribute__((address_space(3))) unsigned int*)&As[b][h * 8192 + (c * 256 + wave * 64) * 8],
                    16, 0, 0);
            }
#pragma unroll
            for (int c = 0; c < 4; c++) {
                int u = c * 256 + wave * 64 + lane;
                const short* gb = Bbase + (size_t)kb * 8192 + u * 8;
                __builtin_amdgcn_global_load_lds(
                    (const __attribute__((address_space(1))) unsigned int*)gb,
                    (__attribute__((address_space(3))) unsigned int*)&Bs[b][h * 8192 + (c * 256 + wave * 64) * 8],
                    16, 0, 0);
            }
        }
    };

    stage(0, 0);
    __syncthreads();
    int cur = 0;
    for (int t = 0; t < KB2; t++) {
        if (t + 1 < KB2) stage(cur ^ 1, t + 1);  // 16 loads fly during 96 MFMAs below
#pragma unroll
        for (int h = 0; h < 2; h++) {
            const short* Ab = &As[cur][h * 8192];
            const short* Bb = &Bs[cur][h * 8192];
            bf16x8 ah[4], al[4], bh[4], bl[4];
#pragma unroll
            for (int mi = 0; mi < 4; mi++) {
                int r = waveM * 64 + mi * 16 + l16;
                int uh = r * 8 + (kg ^ (r & 7));
                int ul = r * 8 + ((4 + kg) ^ (r & 7));
                ah[mi] = *(const bf16x8*)&Ab[uh * 8];
                al[mi] = *(const bf16x8*)&Ab[ul * 8];
            }
#pragma unroll
            for (int ni = 0; ni < 4; ni++) {
                int n = waveN * 64 + ni * 16 + l16;
                bh[ni] = *(const bf16x8*)&Bb[(kg * 128 + n) * 8];
                bl[ni] = *(const bf16x8*)&Bb[(512 + kg * 128 + n) * 8];
            }
            __builtin_amdgcn_s_setprio(1);
#pragma unroll
            for (int mi = 0; mi < 4; mi++)
#pragma unroll
                for (int ni = 0; ni < 4; ni++)
                    acc[mi][ni] = __builtin_amdgcn_mfma_f32_16x16x32_bf16(ah[mi], bh[ni], acc[mi][ni], 0, 0, 0);
#pragma unroll
            for (int mi = 0; mi < 4; mi++)
#pragma unroll
                for (int ni = 0; ni < 4; ni++)
                    acc[mi][ni] = __builtin_amdgcn_mfma_f32_16x16x32_bf16(al[mi], bh[ni], acc[mi][ni], 0, 0, 0);
#pragma unroll
            for (int mi = 0; mi < 4; mi++)
#pragma unroll
                for (int ni = 0; ni < 4; ni++)
                    acc[mi][ni] = __builtin_amdgcn_mfma_f32_16x16x32_bf16(ah[mi], bl[ni], acc[mi][ni], 0, 0, 0);
            __builtin_amdgcn_s_setprio(0);
        }
        __syncthreads();   // drains vmcnt(0)+lgkmcnt(0): next buffer staged, cur fully read
        cur ^= 1;
    }
    const int rbase = m0 + waveM * 64 + (lane >> 4) * 4;
    const int cbase = nt * 128 + waveN * 64 + l16;
#pragma unroll
    for (int mi = 0; mi < 4; mi++)
#pragma unroll
        for (int ni = 0; ni < 4; ni++)
#pragma unroll
            for (int r = 0; r < 4; r++)
                C[(size_t)(rbase + mi * 16 + r) * N + cbase + ni * 16] = acc[mi][ni][r];
}

// ---- hyperbolic linear head, wave-level, E elements per lane (zero-filled if inactive) ----
template<int E>
__device__ float hyper_head_w(float (&v)[E], const float (&bv)[E], float xn, int do_tanh) {
    float p = 0.f;
#pragma unroll
    for (int e = 0; e < E; e++) p += v[e] * v[e];
    float mxn = fmaxf(sqrtf(wsum(p)), 1e-15f);
    float t1 = tanhf((mxn / xn) * artanh_c(xn));
    float ny = fmaxf(t1, 1e-15f);
    float fac = (ny > MAXNORM_F) ? (MAXNORM_F / ny) : 1.0f;
    float sm = t1 * fac / mxn;
    float pa2 = 0.f, pab = 0.f, pb2 = 0.f;
#pragma unroll
    for (int e = 0; e < E; e++) {
        v[e] *= sm;
        pa2 += v[e] * v[e]; pab += v[e] * bv[e]; pb2 += bv[e] * bv[e];
    }
    float a2 = wsum(pa2);
    float ab = wsum(pab);
    float b2 = wsum(pb2);
    float den = fmaxf(1.0f + 2.0f * ab + a2 * b2, 1e-15f);
    float ca = (1.0f + 2.0f * ab + b2) / den;
    float cb = (1.0f - a2) / den;
    float pz2 = 0.f;
#pragma unroll
    for (int e = 0; e < E; e++) {
        v[e] = ca * v[e] + cb * bv[e];
        pz2 += v[e] * v[e];
    }
    float nz = fmaxf(sqrtf(wsum(pz2)), 1e-15f);
    float fz = (nz > MAXNORM_F) ? (MAXNORM_F / nz) : 1.0f;
    float nzp = nz * fz;
    if (!do_tanh) {
#pragma unroll
        for (int e = 0; e < E; e++) v[e] *= fz;
        return nzp;
    }
    float ia = artanh_c(nzp) / nzp * fz;
    float pt2 = 0.f;
#pragma unroll
    for (int e = 0; e < E; e++) {
        v[e] = tanhf(ia * v[e]);
        pt2 += v[e] * v[e];
    }
    float ntn = fmaxf(sqrtf(wsum(pt2)), 1e-15f);
    float to = tanhf(ntn);
    float no = fmaxf(to, 1e-15f);
    float fo = (no > MAXNORM_F) ? (MAXNORM_F / no) : 1.0f;
    float so = to / ntn * fo;
#pragma unroll
    for (int e = 0; e < E; e++) v[e] *= so;
    return fminf(no, MAXNORM_F);
}

// ---- epilogue: wave-per-row, 4 rows/block. N = VPT*256. Writes interleaved [kb][hi|lo]. ----
template<int VPT>
__global__ __launch_bounds__(256) void epi_kernel(
    const float* __restrict__ MX, int N, const float* __restrict__ bias,
    float* __restrict__ xn_io, short* __restrict__ Xout, int ldx,
    float* __restrict__ Fout, int do_tanh) {
    const int lane = threadIdx.x & 63, wave = threadIdx.x >> 6;
    const int row = blockIdx.x * 4 + wave;
    const float* mrow = MX + (size_t)row * N;
    float v[4 * VPT], bv[4 * VPT];
#pragma unroll
    for (int j = 0; j < VPT; j++) {
        int idx = j * 256 + lane * 4;
        float4 t = *(const float4*)(mrow + idx);
        v[4 * j] = t.x; v[4 * j + 1] = t.y; v[4 * j + 2] = t.z; v[4 * j + 3] = t.w;
        float4 tb = *(const float4*)(bias + idx);
        bv[4 * j] = tb.x; bv[4 * j + 1] = tb.y; bv[4 * j + 2] = tb.z; bv[4 * j + 3] = tb.w;
    }
    float xn = xn_io[row];
    float nrm = hyper_head_w<4 * VPT>(v, bv, xn, do_tanh);
    if (Xout) {
        short* orow = Xout + (size_t)row * ldx;
#pragma unroll
        for (int j = 0; j < VPT; j++) {
            int idx = j * 256 + lane * 4;
            int base = (idx >> 5) * 64 + (idx & 31);
            short4 h4, l4;
            short hi;
            hi = f2bf(v[4 * j + 0]); h4.x = hi; l4.x = f2bf(v[4 * j + 0] - bf2f(hi));
            hi = f2bf(v[4 * j + 1]); h4.y = hi; l4.y = f2bf(v[4 * j + 1] - bf2f(hi));
            hi = f2bf(v[4 * j + 2]); h4.z = hi; l4.z = f2bf(v[4 * j + 2] - bf2f(hi));
            hi = f2bf(v[4 * j + 3]); h4.w = hi; l4.w = f2bf(v[4 * j + 3] - bf2f(hi));
            *(short4*)(orow + base) = h4;
            *(short4*)(orow + base + 32) = l4;
        }
    }
    if (Fout) {
        float* orow = Fout + (size_t)row * N;
#pragma unroll
        for (int j = 0; j < VPT; j++) {
            int idx = j * 256 + lane * 4;
            float4 t;
            t.x = v[4 * j]; t.y = v[4 * j + 1]; t.z = v[4 * j + 2]; t.w = v[4 * j + 3];
            *(float4*)(orow + idx) = t;
        }
    }
    if (lane == 0) xn_io[row] = fmaxf(nrm, 1e-15f);
}

// ---- merge + 3-layer Mobius MLP, wave-per-row ----
__global__ __launch_bounds__(256) void merge_mlp_kernel(
    const float* __restrict__ head, const float* __restrict__ tail,
    const float* __restrict__ nh_arr, const float* __restrict__ nt_arr,
    const float* __restrict__ Wm1, const float* __restrict__ bm1,
    const float* __restrict__ Wm2, const float* __restrict__ bm2,
    const float* __restrict__ Wm3, const float* __restrict__ bm3,
    float* __restrict__ out) {
    __shared__ float xs[4][256];
    const int lane = threadIdx.x & 63, wave = threadIdx.x >> 6;
    const int row = blockIdx.x * 4 + wave;
    float* x = xs[wave];
    float4 h4 = *(const float4*)(head + (size_t)row * 256 + lane * 4);
    float4 t4 = *(const float4*)(tail + (size_t)row * 256 + lane * 4);
    float A[4] = {h4.x, h4.y, h4.z, h4.w};
    float Bv[4] = {t4.x, t4.y, t4.z, t4.w};
    float nh = nh_arr[row], ntl = nt_arr[row];
    float sh = tanhf(0.27f * artanh_c(nh)) / nh;
    float st = tanhf(0.73f * artanh_c(ntl)) / ntl;
    float px2 = 0.f, py2 = 0.f, pxy = 0.f;
#pragma unroll
    for (int e = 0; e < 4; e++) {
        A[e] *= sh; Bv[e] *= st;
        px2 += A[e] * A[e]; py2 += Bv[e] * Bv[e]; pxy += A[e] * Bv[e];
    }
    float x2 = wsum(px2), y2 = wsum(py2), xy = wsum(pxy);
    float den = fmaxf(1.0f + 2.0f * xy + x2 * y2, 1e-15f);
    float ca = (1.0f + 2.0f * xy + y2) / den, cb = (1.0f - x2) / den;
    float z[4]; float pz2 = 0.f;
#pragma unroll
    for (int e = 0; e < 4; e++) { z[e] = ca * A[e] + cb * Bv[e]; pz2 += z[e] * z[e]; }
    float nz = fmaxf(sqrtf(wsum(pz2)), 1e-15f);
    float fz = (nz > MAXNORM_F) ? (MAXNORM_F / nz) : 1.0f;
    float nmid = nz * fz;
    float4 zs; zs.x = z[0] * fz; zs.y = z[1] * fz; zs.z = z[2] * fz; zs.w = z[3] * fz;
    *(float4*)(x + lane * 4) = zs;

    float v[1], bvv[1];
    {
        float acc = 0.f;
        for (int k = 0; k < 256; k++) acc += x[k] * Wm1[k * 64 + lane];
        v[0] = acc; bvv[0] = bm1[lane];
    }
    float n1 = hyper_head_w<1>(v, bvv, nmid, 1);
    x[lane] = v[0];
    {
        float acc = 0.f;
        if (lane < 32) { for (int k = 0; k < 64; k++) acc += x[k] * Wm2[k * 32 + lane]; }
        v[0] = (lane < 32) ? acc : 0.f;
        bvv[0] = (lane < 32) ? bm2[lane] : 0.f;
    }
    float n2 = hyper_head_w<1>(v, bvv, n1, 1);
    x[lane] = (lane < 32) ? v[0] : 0.f;
    {
        float acc = 0.f;
        if (lane < 2) { for (int k = 0; k < 32; k++) acc += x[k] * Wm3[k * 2 + lane]; }
        v[0] = (lane < 2) ? acc : 0.f;
        bvv[0] = (lane < 2) ? bm3[lane] : 0.f;
    }
    hyper_head_w<1>(v, bvv, n2, 0);
    if (lane < 2) out[(size_t)row * 2 + lane] = v[0];
}

// ---- launch ----
extern "C" void kernel_launch(void* const* d_in, const int* in_sizes, int n_in,
                              void* d_out, int out_size, void* d_ws, size_t ws_size,
                              hipStream_t stream) {
    const float* dch = (const float*)d_in[0];
    const float* dpc = (const float*)d_in[1];
    const float* dmc = (const float*)d_in[2];
    const float* dec = (const float*)d_in[3];
    const float* tes = (const float*)d_in[4];
    const float* tpc = (const float*)d_in[5];
    const float* tme = (const float*)d_in[6];
    const float* Wd1 = (const float*)d_in[7];  const float* bd1 = (const float*)d_in[8];
    const float* Wd2 = (const float*)d_in[9];  const float* bd2 = (const float*)d_in[10];
    const float* Wd3 = (const float*)d_in[11]; const float* bd3 = (const float*)d_in[12];
    const float* Wt1 = (const float*)d_in[13]; const float* bt1 = (const float*)d_in[14];
    const float* Wt2 = (const float*)d_in[15]; const float* bt2 = (const float*)d_in[16];
    const float* Wt3 = (const float*)d_in[17]; const float* bt3 = (const float*)d_in[18];
    const float* Wm1 = (const float*)d_in[19]; const float* bm1 = (const float*)d_in[20];
    const float* Wm2 = (const float*)d_in[21]; const float* bm2 = (const float*)d_in[22];
    const float* Wm3 = (const float*)d_in[23]; const float* bm3 = (const float*)d_in[24];

    const int B = in_sizes[0] / 768;   // 16384

    float* mx  = (float*)d_ws;                          // B*1024 f32
    short* xb  = (short*)(mx + (size_t)B * 1024);       // B*3456 bf16 (shared both branches)
    float* hf_d = (float*)(xb + (size_t)B * 3456);      // B*256 f32
    float* hf_t = hf_d + (size_t)B * 256;
    float* xn_d = hf_t + (size_t)B * 256;
    float* xn_t = xn_d + B;
    // packed weights: [ntile][KB][2][4096] shorts
    short* wp_d1 = (short*)(xn_t + B);                  // 8*54*8192
    short* wp_d2 = wp_d1 + 8 * 54 * 8192;               // 4*32*8192
    short* wp_d3 = wp_d2 + 4 * 32 * 8192;               // 2*16*8192
    short* wp_t1 = wp_d3 + 2 * 16 * 8192;
    short* wp_t2 = wp_t1 + 8 * 54 * 8192;
    short* wp_t3 = wp_t2 + 4 * 32 * 8192;

    dim3 blk(256);
    int e1 = 8 * 54 * 8192, e2 = 4 * 32 * 8192, e3 = 2 * 16 * 8192;
    hipLaunchKernelGGL(pack_w_kernel, dim3((e1 + 255) / 256), blk, 0, stream, Wd1, 1711, 54, 1024, wp_d1);
    hipLaunchKernelGGL(pack_w_kernel, dim3((e2 + 255) / 256), blk, 0, stream, Wd2, 1024, 32, 512, wp_d2);
    hipLaunchKernelGGL(pack_w_kernel, dim3((e3 + 255) / 256), blk, 0, stream, Wd3, 512, 16, 256, wp_d3);
    hipLaunchKernelGGL(pack_w_kernel, dim3((e1 + 255) / 256), blk, 0, stream, Wt1, 1711, 54, 1024, wp_t1);
    hipLaunchKernelGGL(pack_w_kernel, dim3((e2 + 255) / 256), blk, 0, stream, Wt2, 1024, 32, 512, wp_t2);
    hipLaunchKernelGGL(pack_w_kernel, dim3((e3 + 255) / 256), blk, 0, stream, Wt3, 512, 16, 256, wp_t3);

    // ---- drug branch ----
    hipLaunchKernelGGL(prep_kernel, dim3(B / 4), blk, 0, stream,
                       dch, dpc, dmc, dec, 768, 11, 167, 765, xb, xn_d);
    hipLaunchKernelGGL(gemm_mfma, dim3(8 * (B / 128)), blk, 0, stream, xb, 3456, 54, wp_d1, mx, 1024, 3);
    hipLaunchKernelGGL((epi_kernel<4>), dim3(B / 4), blk, 0, stream, mx, 1024, bd1, xn_d, xb, 2048, (float*)nullptr, 1);
    hipLaunchKernelGGL(gemm_mfma, dim3(4 * (B / 128)), blk, 0, stream, xb, 2048, 32, wp_d2, mx, 512, 2);
    hipLaunchKernelGGL((epi_kernel<2>), dim3(B / 4), blk, 0, stream, mx, 512, bd2, xn_d, xb, 1024, (float*)nullptr, 1);
    hipLaunchKernelGGL(gemm_mfma, dim3(2 * (B / 128)), blk, 0, stream, xb, 1024, 16, wp_d3, mx, 256, 1);
    hipLaunchKernelGGL((epi_kernel<1>), dim3(B / 4), blk, 0, stream, mx, 256, bd3, xn_d, (short*)nullptr, 0, hf_d, 0);

    // ---- target branch (reuses xb, mx) ----
    hipLaunchKernelGGL(prep_kernel, dim3(B / 4), blk, 0, stream,
                       tes, tpc, tme, (const float*)nullptr, 1280, 11, 420, 0, xb, xn_t);
    hipLaunchKernelGGL(gemm_mfma, dim3(8 * (B / 128)), blk, 0, stream, xb, 3456, 54, wp_t1, mx, 1024, 3);
    hipLaunchKernelGGL((epi_kernel<4>), dim3(B / 4), blk, 0, stream, mx, 1024, bt1, xn_t, xb, 2048, (float*)nullptr, 1);
    hipLaunchKernelGGL(gemm_mfma, dim3(4 * (B / 128)), blk, 0, stream, xb, 2048, 32, wp_t2, mx, 512, 2);
    hipLaunchKernelGGL((epi_kernel<2>), dim3(B / 4), blk, 0, stream, mx, 512, bt2, xn_t, xb, 1024, (float*)nullptr, 1);
    hipLaunchKernelGGL(gemm_mfma, dim3(2 * (B / 128)), blk, 0, stream, xb, 1024, 16, wp_t3, mx, 256, 1);
    hipLaunchKernelGGL((epi_kernel<1>), dim3(B / 4), blk, 0, stream, mx, 256, bt3, xn_t, (short*)nullptr, 0, hf_t, 0);

    // ---- merge + MLP -> out ----
    hipLaunchKernelGGL(merge_mlp_kernel, dim3(B / 4), blk, 0, stream,
                       hf_d, hf_t, xn_d, xn_t, Wm1, bm1, Wm2, bm2, Wm3, bm3, (float*)d_out);
}

// Round 4
// 1074.945 us; speedup vs baseline: 1.0143x; 1.0143x over previous
//
#include <hip/hip_runtime.h>
#include <math.h>

#define MAXNORM_F 0.996f

typedef __attribute__((ext_vector_type(8))) short bf16x8;
typedef __attribute__((ext_vector_type(4))) float f32x4;

__device__ __forceinline__ short f2bf(float f) {
    union { float f; unsigned u; } v; v.f = f;
    unsigned r = v.u + 0x7FFF + ((v.u >> 16) & 1);
    return (short)(r >> 16);
}
__device__ __forceinline__ float bf2f(short s) {
    union { unsigned u; float f; } v; v.u = ((unsigned)(unsigned short)s) << 16;
    return v.f;
}

__device__ __forceinline__ float artanh_c(float x) {
    const float lim = 1.0f - 1e-5f;
    x = fminf(fmaxf(x, -lim), lim);
    return 0.5f * logf((1.0f + x) / (1.0f - x));
}

// full 64-lane wave sum, result in all lanes
__device__ __forceinline__ float wsum(float v) {
#pragma unroll
    for (int m = 32; m > 0; m >>= 1) v += __shfl_xor(v, m, 64);
    return v;
}

// ---- weight pack: fp32 [K][N] -> bf16 [ntile][kb][seg(2:hi,lo)][kg(4)][n(128)][j(8)] ----
__global__ __launch_bounds__(256) void pack_w_kernel(
    const float* __restrict__ W, int Kreal, int KB, int N, short* __restrict__ out) {
    int e = blockIdx.x * 256 + threadIdx.x;
    int total = (N >> 7) * KB * 2 * 4096;
    if (e >= total) return;
    int j   = e & 7;
    int n   = (e >> 3) & 127;
    int kg  = (e >> 10) & 3;
    int seg = (e >> 12) & 1;
    int rest = e >> 13;
    int kb  = rest % KB;
    int nt  = rest / KB;
    int k = (kb << 5) + (kg << 3) + j;
    int col = (nt << 7) + n;
    float v = (k < Kreal) ? W[(size_t)k * N + col] : 0.f;
    short hi = f2bf(v);
    out[e] = (seg == 0) ? hi : f2bf(v - bf2f(hi));
}

// ---- prep: zscore + concat + expmap0 -> bf16, interleaved [kb][hi32|lo32]. Wave-per-row. ----
__global__ __launch_bounds__(256) void prep_kernel(
    const float* __restrict__ s0, const float* __restrict__ s1,
    const float* __restrict__ s2, const float* __restrict__ s3,
    int f0, int f1, int f2, int f3,
    short* __restrict__ Xb, float* __restrict__ xn_out) {
    __shared__ float xbuf[4][1712];
    const int lane = threadIdx.x & 63, wave = threadIdx.x >> 6;
    const int row = blockIdx.x * 4 + wave;
    float* xb = xbuf[wave];
    const float* srcs[4] = {s0, s1, s2, s3};
    const int fs[4] = {f0, f1, f2, f3};
    int off = 0;
    for (int b = 0; b < 4; b++) {
        int F = fs[b];
        if (F == 0) break;
        const float* srow = srcs[b] + (size_t)row * F;
        float ps = 0.f;
        for (int i = lane; i < F; i += 64) { float v = srow[i]; xb[off + i] = v; ps += v; }
        float mean = wsum(ps) / (float)F;
        float pq = 0.f;
        for (int i = lane; i < F; i += 64) { float d = xb[off + i] - mean; pq += d * d; }
        float var = wsum(pq) / (float)(F - 1);
        float inv = 1.0f / (sqrtf(var) + 1e-8f);
        for (int i = lane; i < F; i += 64) xb[off + i] = (xb[off + i] - mean) * inv;
        off += F;
    }
    float pn = 0.f;
    for (int i = lane; i < 1711; i += 64) pn += xb[i] * xb[i];
    float n = fmaxf(sqrtf(wsum(pn)), 1e-15f);
    float t = tanhf(n);
    float sc = t / n;
    short* xrow = Xb + (size_t)row * 3456;   // [kb(54)][hi(32)|lo(32)]
    for (int i = lane; i < 1728; i += 64) {
        float v = (i < 1711) ? sc * xb[i] : 0.f;
        short hi = f2bf(v);
        int base = (i >> 5) * 64 + (i & 31);
        xrow[base] = hi;
        xrow[base + 32] = f2bf(v - bf2f(hi));
    }
    if (lane == 0) xn_out[row] = fmaxf(t, 1e-15f);
}

// ---- bf16 MFMA GEMM, fused 3-term split precision, line-dense A, XCD swizzle ----
// A: bf16 [M][lda], lda = 2*Kpad, layout [kb][hi32|lo32] per row (128B lines).
// Wp packed per pack_w_kernel. Grid: 1D, NT*M/128 blocks, NT = 1<<ntShift.
// A-only LDS ring (2 x 16KB, depth-1 prefetch). B (weights) bypass LDS: each
// wave loads its fragments global->register, double-buffered one kb ahead in
// NAMED reg buffers (no runtime indexing). The per-iteration barrier drain now
// covers only 32KB/CU of A staging (~585cyc) + L1/L2-hit B loads, inside the
// ~1546cyc MFMA window. Round-3 lesson: keep 2 blocks/CU (LDS 32KB/block).
// Requires KB even (54/32/16 all are).
__global__ __launch_bounds__(256) void gemm_mfma(
    const short* __restrict__ A, int lda, int KB,
    const short* __restrict__ Wp,
    float* __restrict__ C, int N, int ntShift) {
    __shared__ short As[2][8192];  // 128 rows x 64 shorts; 16B-unit slot = p ^ (row&7)
    const int tid = threadIdx.x;
    const int lane = tid & 63;
    const int wave = __builtin_amdgcn_readfirstlane(tid >> 6);
    const int waveM = wave >> 1, waveN = wave & 1;
    const int kg = lane >> 4, l16 = lane & 15;

    // XCD-aware swizzle: same m-strip -> same XCD, consecutive in time
    int flat = blockIdx.x;
    int xcd = flat & 7;
    int idx = flat >> 3;
    int q = idx >> ntShift;
    int nt = idx & ((1 << ntShift) - 1);
    int mt = q * 8 + xcd;
    const int m0 = mt * 128;

    f32x4 acc[4][4] = {};
    const short* Bbase = Wp + (size_t)nt * KB * 8192;

    // stage A kb into ring buffer b: 1024 x 16B units; unit u holds chunk
    // p = (u&7)^(row&7) of row u>>3 (swizzle lives in the per-lane GLOBAL addr).
    auto stageA = [&](int b, int kb) {
#pragma unroll
        for (int c = 0; c < 4; c++) {
            int u = c * 256 + wave * 64 + lane;
            int row = u >> 3;
            int p = (u & 7) ^ (row & 7);
            const short* ga = A + (size_t)(m0 + row) * lda + kb * 64 + p * 8;
            __builtin_amdgcn_global_load_lds(
                (const __attribute__((address_space(1))) unsigned int*)ga,
                (__attribute__((address_space(3))) unsigned int*)&As[b][(c * 256 + wave * 64) * 8],
                16, 0, 0);
        }
    };

    // direct global->reg B fragments for this wave: for fixed (kg,ni) the 16
    // lanes read 16 consecutive 16B chunks (256B coalesced, L1/L2-hot).
    const int nb = waveN * 64 + l16;
    auto loadB = [&](int kb, bf16x8 (&bh)[4], bf16x8 (&bl)[4]) {
        const short* kbase = Bbase + (size_t)kb * 8192;
#pragma unroll
        for (int ni = 0; ni < 4; ni++) {
            int n = nb + ni * 16;
            bh[ni] = *(const bf16x8*)(kbase + (kg * 128 + n) * 8);
            bl[ni] = *(const bf16x8*)(kbase + (512 + kg * 128 + n) * 8);
        }
    };

    // ds_read A fragments + 3-term MFMA cluster from ring buffer cb
    auto compute = [&](int cb, const bf16x8 (&bh)[4], const bf16x8 (&bl)[4]) {
        bf16x8 ah[4], al[4];
#pragma unroll
        for (int mi = 0; mi < 4; mi++) {
            int r = waveM * 64 + mi * 16 + l16;
            int uh = r * 8 + (kg ^ (r & 7));
            int ul = r * 8 + ((4 + kg) ^ (r & 7));
            ah[mi] = *(const bf16x8*)&As[cb][uh * 8];
            al[mi] = *(const bf16x8*)&As[cb][ul * 8];
        }
        __builtin_amdgcn_s_setprio(1);
#pragma unroll
        for (int mi = 0; mi < 4; mi++)
#pragma unroll
            for (int ni = 0; ni < 4; ni++)
                acc[mi][ni] = __builtin_amdgcn_mfma_f32_16x16x32_bf16(ah[mi], bh[ni], acc[mi][ni], 0, 0, 0);
#pragma unroll
        for (int mi = 0; mi < 4; mi++)
#pragma unroll
            for (int ni = 0; ni < 4; ni++)
                acc[mi][ni] = __builtin_amdgcn_mfma_f32_16x16x32_bf16(al[mi], bh[ni], acc[mi][ni], 0, 0, 0);
#pragma unroll
        for (int mi = 0; mi < 4; mi++)
#pragma unroll
            for (int ni = 0; ni < 4; ni++)
                acc[mi][ni] = __builtin_amdgcn_mfma_f32_16x16x32_bf16(ah[mi], bl[ni], acc[mi][ni], 0, 0, 0);
        __builtin_amdgcn_s_setprio(0);
    };

    bf16x8 bh0[4], bl0[4], bh1[4], bl1[4];
    stageA(0, 0);
    loadB(0, bh0, bl0);
    __syncthreads();
    int cur = 0;
    // unrolled x2 with named B reg buffers (KB even)
    for (int t = 0; t < KB; t += 2) {
        // ---- kb = t: B in bh0/bl0; prefetch A(t+1)->ring, B(t+1)->bh1 ----
        stageA(cur ^ 1, t + 1);
        loadB(t + 1, bh1, bl1);
        compute(cur, bh0, bl0);
        __syncthreads();   // drains A-stage of t+1 (32KB/CU) + B loads
        cur ^= 1;
        // ---- kb = t+1: B in bh1/bl1; prefetch A(t+2), B(t+2)->bh0 ----
        if (t + 2 < KB) {
            stageA(cur ^ 1, t + 2);
            loadB(t + 2, bh0, bl0);
        }
        compute(cur, bh1, bl1);
        __syncthreads();
        cur ^= 1;
    }
    const int rbase = m0 + waveM * 64 + (lane >> 4) * 4;
    const int cbase = nt * 128 + waveN * 64 + l16;
#pragma unroll
    for (int mi = 0; mi < 4; mi++)
#pragma unroll
        for (int ni = 0; ni < 4; ni++)
#pragma unroll
            for (int r = 0; r < 4; r++)
                C[(size_t)(rbase + mi * 16 + r) * N + cbase + ni * 16] = acc[mi][ni][r];
}

// ---- hyperbolic linear head, wave-level, E elements per lane (zero-filled if inactive) ----
template<int E>
__device__ float hyper_head_w(float (&v)[E], const float (&bv)[E], float xn, int do_tanh) {
    float p = 0.f;
#pragma unroll
    for (int e = 0; e < E; e++) p += v[e] * v[e];
    float mxn = fmaxf(sqrtf(wsum(p)), 1e-15f);
    float t1 = tanhf((mxn / xn) * artanh_c(xn));
    float ny = fmaxf(t1, 1e-15f);
    float fac = (ny > MAXNORM_F) ? (MAXNORM_F / ny) : 1.0f;
    float sm = t1 * fac / mxn;
    float pa2 = 0.f, pab = 0.f, pb2 = 0.f;
#pragma unroll
    for (int e = 0; e < E; e++) {
        v[e] *= sm;
        pa2 += v[e] * v[e]; pab += v[e] * bv[e]; pb2 += bv[e] * bv[e];
    }
    float a2 = wsum(pa2);
    float ab = wsum(pab);
    float b2 = wsum(pb2);
    float den = fmaxf(1.0f + 2.0f * ab + a2 * b2, 1e-15f);
    float ca = (1.0f + 2.0f * ab + b2) / den;
    float cb = (1.0f - a2) / den;
    float pz2 = 0.f;
#pragma unroll
    for (int e = 0; e < E; e++) {
        v[e] = ca * v[e] + cb * bv[e];
        pz2 += v[e] * v[e];
    }
    float nz = fmaxf(sqrtf(wsum(pz2)), 1e-15f);
    float fz = (nz > MAXNORM_F) ? (MAXNORM_F / nz) : 1.0f;
    float nzp = nz * fz;
    if (!do_tanh) {
#pragma unroll
        for (int e = 0; e < E; e++) v[e] *= fz;
        return nzp;
    }
    float ia = artanh_c(nzp) / nzp * fz;
    float pt2 = 0.f;
#pragma unroll
    for (int e = 0; e < E; e++) {
        v[e] = tanhf(ia * v[e]);
        pt2 += v[e] * v[e];
    }
    float ntn = fmaxf(sqrtf(wsum(pt2)), 1e-15f);
    float to = tanhf(ntn);
    float no = fmaxf(to, 1e-15f);
    float fo = (no > MAXNORM_F) ? (MAXNORM_F / no) : 1.0f;
    float so = to / ntn * fo;
#pragma unroll
    for (int e = 0; e < E; e++) v[e] *= so;
    return fminf(no, MAXNORM_F);
}

// ---- epilogue: wave-per-row, 4 rows/block. N = VPT*256. Writes interleaved [kb][hi|lo]. ----
template<int VPT>
__global__ __launch_bounds__(256) void epi_kernel(
    const float* __restrict__ MX, int N, const float* __restrict__ bias,
    float* __restrict__ xn_io, short* __restrict__ Xout, int ldx,
    float* __restrict__ Fout, int do_tanh) {
    const int lane = threadIdx.x & 63, wave = threadIdx.x >> 6;
    const int row = blockIdx.x * 4 + wave;
    const float* mrow = MX + (size_t)row * N;
    float v[4 * VPT], bv[4 * VPT];
#pragma unroll
    for (int j = 0; j < VPT; j++) {
        int idx = j * 256 + lane * 4;
        float4 t = *(const float4*)(mrow + idx);
        v[4 * j] = t.x; v[4 * j + 1] = t.y; v[4 * j + 2] = t.z; v[4 * j + 3] = t.w;
        float4 tb = *(const float4*)(bias + idx);
        bv[4 * j] = tb.x; bv[4 * j + 1] = tb.y; bv[4 * j + 2] = tb.z; bv[4 * j + 3] = tb.w;
    }
    float xn = xn_io[row];
    float nrm = hyper_head_w<4 * VPT>(v, bv, xn, do_tanh);
    if (Xout) {
        short* orow = Xout + (size_t)row * ldx;
#pragma unroll
        for (int j = 0; j < VPT; j++) {
            int idx = j * 256 + lane * 4;
            int base = (idx >> 5) * 64 + (idx & 31);
            short4 h4, l4;
            short hi;
            hi = f2bf(v[4 * j + 0]); h4.x = hi; l4.x = f2bf(v[4 * j + 0] - bf2f(hi));
            hi = f2bf(v[4 * j + 1]); h4.y = hi; l4.y = f2bf(v[4 * j + 1] - bf2f(hi));
            hi = f2bf(v[4 * j + 2]); h4.z = hi; l4.z = f2bf(v[4 * j + 2] - bf2f(hi));
            hi = f2bf(v[4 * j + 3]); h4.w = hi; l4.w = f2bf(v[4 * j + 3] - bf2f(hi));
            *(short4*)(orow + base) = h4;
            *(short4*)(orow + base + 32) = l4;
        }
    }
    if (Fout) {
        float* orow = Fout + (size_t)row * N;
#pragma unroll
        for (int j = 0; j < VPT; j++) {
            int idx = j * 256 + lane * 4;
            float4 t;
            t.x = v[4 * j]; t.y = v[4 * j + 1]; t.z = v[4 * j + 2]; t.w = v[4 * j + 3];
            *(float4*)(orow + idx) = t;
        }
    }
    if (lane == 0) xn_io[row] = fmaxf(nrm, 1e-15f);
}

// ---- merge + 3-layer Mobius MLP, wave-per-row ----
__global__ __launch_bounds__(256) void merge_mlp_kernel(
    const float* __restrict__ head, const float* __restrict__ tail,
    const float* __restrict__ nh_arr, const float* __restrict__ nt_arr,
    const float* __restrict__ Wm1, const float* __restrict__ bm1,
    const float* __restrict__ Wm2, const float* __restrict__ bm2,
    const float* __restrict__ Wm3, const float* __restrict__ bm3,
    float* __restrict__ out) {
    __shared__ float xs[4][256];
    const int lane = threadIdx.x & 63, wave = threadIdx.x >> 6;
    const int row = blockIdx.x * 4 + wave;
    float* x = xs[wave];
    float4 h4 = *(const float4*)(head + (size_t)row * 256 + lane * 4);
    float4 t4 = *(const float4*)(tail + (size_t)row * 256 + lane * 4);
    float A[4] = {h4.x, h4.y, h4.z, h4.w};
    float Bv[4] = {t4.x, t4.y, t4.z, t4.w};
    float nh = nh_arr[row], ntl = nt_arr[row];
    float sh = tanhf(0.27f * artanh_c(nh)) / nh;
    float st = tanhf(0.73f * artanh_c(ntl)) / ntl;
    float px2 = 0.f, py2 = 0.f, pxy = 0.f;
#pragma unroll
    for (int e = 0; e < 4; e++) {
        A[e] *= sh; Bv[e] *= st;
        px2 += A[e] * A[e]; py2 += Bv[e] * Bv[e]; pxy += A[e] * Bv[e];
    }
    float x2 = wsum(px2), y2 = wsum(py2), xy = wsum(pxy);
    float den = fmaxf(1.0f + 2.0f * xy + x2 * y2, 1e-15f);
    float ca = (1.0f + 2.0f * xy + y2) / den, cb = (1.0f - x2) / den;
    float z[4]; float pz2 = 0.f;
#pragma unroll
    for (int e = 0; e < 4; e++) { z[e] = ca * A[e] + cb * Bv[e]; pz2 += z[e] * z[e]; }
    float nz = fmaxf(sqrtf(wsum(pz2)), 1e-15f);
    float fz = (nz > MAXNORM_F) ? (MAXNORM_F / nz) : 1.0f;
    float nmid = nz * fz;
    float4 zs; zs.x = z[0] * fz; zs.y = z[1] * fz; zs.z = z[2] * fz; zs.w = z[3] * fz;
    *(float4*)(x + lane * 4) = zs;

    float v[1], bvv[1];
    {
        float acc = 0.f;
        for (int k = 0; k < 256; k++) acc += x[k] * Wm1[k * 64 + lane];
        v[0] = acc; bvv[0] = bm1[lane];
    }
    float n1 = hyper_head_w<1>(v, bvv, nmid, 1);
    x[lane] = v[0];
    {
        float acc = 0.f;
        if (lane < 32) { for (int k = 0; k < 64; k++) acc += x[k] * Wm2[k * 32 + lane]; }
        v[0] = (lane < 32) ? acc : 0.f;
        bvv[0] = (lane < 32) ? bm2[lane] : 0.f;
    }
    float n2 = hyper_head_w<1>(v, bvv, n1, 1);
    x[lane] = (lane < 32) ? v[0] : 0.f;
    {
        float acc = 0.f;
        if (lane < 2) { for (int k = 0; k < 32; k++) acc += x[k] * Wm3[k * 2 + lane]; }
        v[0] = (lane < 2) ? acc : 0.f;
        bvv[0] = (lane < 2) ? bm3[lane] : 0.f;
    }
    hyper_head_w<1>(v, bvv, n2, 0);
    if (lane < 2) out[(size_t)row * 2 + lane] = v[0];
}

// ---- launch ----
extern "C" void kernel_launch(void* const* d_in, const int* in_sizes, int n_in,
                              void* d_out, int out_size, void* d_ws, size_t ws_size,
                              hipStream_t stream) {
    const float* dch = (const float*)d_in[0];
    const float* dpc = (const float*)d_in[1];
    const float* dmc = (const float*)d_in[2];
    const float* dec = (const float*)d_in[3];
    const float* tes = (const float*)d_in[4];
    const float* tpc = (const float*)d_in[5];
    const float* tme = (const float*)d_in[6];
    const float* Wd1 = (const float*)d_in[7];  const float* bd1 = (const float*)d_in[8];
    const float* Wd2 = (const float*)d_in[9];  const float* bd2 = (const float*)d_in[10];
    const float* Wd3 = (const float*)d_in[11]; const float* bd3 = (const float*)d_in[12];
    const float* Wt1 = (const float*)d_in[13]; const float* bt1 = (const float*)d_in[14];
    const float* Wt2 = (const float*)d_in[15]; const float* bt2 = (const float*)d_in[16];
    const float* Wt3 = (const float*)d_in[17]; const float* bt3 = (const float*)d_in[18];
    const float* Wm1 = (const float*)d_in[19]; const float* bm1 = (const float*)d_in[20];
    const float* Wm2 = (const float*)d_in[21]; const float* bm2 = (const float*)d_in[22];
    const float* Wm3 = (const float*)d_in[23]; const float* bm3 = (const float*)d_in[24];

    const int B = in_sizes[0] / 768;   // 16384

    float* mx  = (float*)d_ws;                          // B*1024 f32
    short* xb  = (short*)(mx + (size_t)B * 1024);       // B*3456 bf16 (shared both branches)
    float* hf_d = (float*)(xb + (size_t)B * 3456);      // B*256 f32
    float* hf_t = hf_d + (size_t)B * 256;
    float* xn_d = hf_t + (size_t)B * 256;
    float* xn_t = xn_d + B;
    // packed weights: [ntile][KB][2][4096] shorts
    short* wp_d1 = (short*)(xn_t + B);                  // 8*54*8192
    short* wp_d2 = wp_d1 + 8 * 54 * 8192;               // 4*32*8192
    short* wp_d3 = wp_d2 + 4 * 32 * 8192;               // 2*16*8192
    short* wp_t1 = wp_d3 + 2 * 16 * 8192;
    short* wp_t2 = wp_t1 + 8 * 54 * 8192;
    short* wp_t3 = wp_t2 + 4 * 32 * 8192;

    dim3 blk(256);
    int e1 = 8 * 54 * 8192, e2 = 4 * 32 * 8192, e3 = 2 * 16 * 8192;
    hipLaunchKernelGGL(pack_w_kernel, dim3((e1 + 255) / 256), blk, 0, stream, Wd1, 1711, 54, 1024, wp_d1);
    hipLaunchKernelGGL(pack_w_kernel, dim3((e2 + 255) / 256), blk, 0, stream, Wd2, 1024, 32, 512, wp_d2);
    hipLaunchKernelGGL(pack_w_kernel, dim3((e3 + 255) / 256), blk, 0, stream, Wd3, 512, 16, 256, wp_d3);
    hipLaunchKernelGGL(pack_w_kernel, dim3((e1 + 255) / 256), blk, 0, stream, Wt1, 1711, 54, 1024, wp_t1);
    hipLaunchKernelGGL(pack_w_kernel, dim3((e2 + 255) / 256), blk, 0, stream, Wt2, 1024, 32, 512, wp_t2);
    hipLaunchKernelGGL(pack_w_kernel, dim3((e3 + 255) / 256), blk, 0, stream, Wt3, 512, 16, 256, wp_t3);

    // ---- drug branch ----
    hipLaunchKernelGGL(prep_kernel, dim3(B / 4), blk, 0, stream,
                       dch, dpc, dmc, dec, 768, 11, 167, 765, xb, xn_d);
    hipLaunchKernelGGL(gemm_mfma, dim3(8 * (B / 128)), blk, 0, stream, xb, 3456, 54, wp_d1, mx, 1024, 3);
    hipLaunchKernelGGL((epi_kernel<4>), dim3(B / 4), blk, 0, stream, mx, 1024, bd1, xn_d, xb, 2048, (float*)nullptr, 1);
    hipLaunchKernelGGL(gemm_mfma, dim3(4 * (B / 128)), blk, 0, stream, xb, 2048, 32, wp_d2, mx, 512, 2);
    hipLaunchKernelGGL((epi_kernel<2>), dim3(B / 4), blk, 0, stream, mx, 512, bd2, xn_d, xb, 1024, (float*)nullptr, 1);
    hipLaunchKernelGGL(gemm_mfma, dim3(2 * (B / 128)), blk, 0, stream, xb, 1024, 16, wp_d3, mx, 256, 1);
    hipLaunchKernelGGL((epi_kernel<1>), dim3(B / 4), blk, 0, stream, mx, 256, bd3, xn_d, (short*)nullptr, 0, hf_d, 0);

    // ---- target branch (reuses xb, mx) ----
    hipLaunchKernelGGL(prep_kernel, dim3(B / 4), blk, 0, stream,
                       tes, tpc, tme, (const float*)nullptr, 1280, 11, 420, 0, xb, xn_t);
    hipLaunchKernelGGL(gemm_mfma, dim3(8 * (B / 128)), blk, 0, stream, xb, 3456, 54, wp_t1, mx, 1024, 3);
    hipLaunchKernelGGL((epi_kernel<4>), dim3(B / 4), blk, 0, stream, mx, 1024, bt1, xn_t, xb, 2048, (float*)nullptr, 1);
    hipLaunchKernelGGL(gemm_mfma, dim3(4 * (B / 128)), blk, 0, stream, xb, 2048, 32, wp_t2, mx, 512, 2);
    hipLaunchKernelGGL((epi_kernel<2>), dim3(B / 4), blk, 0, stream, mx, 512, bt2, xn_t, xb, 1024, (float*)nullptr, 1);
    hipLaunchKernelGGL(gemm_mfma, dim3(2 * (B / 128)), blk, 0, stream, xb, 1024, 16, wp_t3, mx, 256, 1);
    hipLaunchKernelGGL((epi_kernel<1>), dim3(B / 4), blk, 0, stream, mx, 256, bt3, xn_t, (short*)nullptr, 0, hf_t, 0);

    // ---- merge + MLP -> out ----
    hipLaunchKernelGGL(merge_mlp_kernel, dim3(B / 4), blk, 0, stream,
                       hf_d, hf_t, xn_d, xn_t, Wm1, bm1, Wm2, bm2, Wm3, bm3, (float*)d_out);
}

// Round 5
// 1037.748 us; speedup vs baseline: 1.0507x; 1.0358x over previous
//
#include <hip/hip_runtime.h>
#include <math.h>

#define MAXNORM_F 0.996f

typedef __attribute__((ext_vector_type(8))) short bf16x8;
typedef __attribute__((ext_vector_type(4))) float f32x4;

__device__ __forceinline__ short f2bf(float f) {
    union { float f; unsigned u; } v; v.f = f;
    unsigned r = v.u + 0x7FFF + ((v.u >> 16) & 1);
    return (short)(r >> 16);
}
__device__ __forceinline__ float bf2f(short s) {
    union { unsigned u; float f; } v; v.u = ((unsigned)(unsigned short)s) << 16;
    return v.f;
}

__device__ __forceinline__ float artanh_c(float x) {
    const float lim = 1.0f - 1e-5f;
    x = fminf(fmaxf(x, -lim), lim);
    return 0.5f * logf((1.0f + x) / (1.0f - x));
}

// full 64-lane wave sum, result in all lanes
__device__ __forceinline__ float wsum(float v) {
#pragma unroll
    for (int m = 32; m > 0; m >>= 1) v += __shfl_xor(v, m, 64);
    return v;
}

// ---- weight pack: fp32 [K][N] -> bf16 [ntile][kb][seg(2:hi,lo)][kg(4)][n(128)][j(8)] ----
__global__ __launch_bounds__(256) void pack_w_kernel(
    const float* __restrict__ W, int Kreal, int KB, int N, short* __restrict__ out) {
    int e = blockIdx.x * 256 + threadIdx.x;
    int total = (N >> 7) * KB * 2 * 4096;
    if (e >= total) return;
    int j   = e & 7;
    int n   = (e >> 3) & 127;
    int kg  = (e >> 10) & 3;
    int seg = (e >> 12) & 1;
    int rest = e >> 13;
    int kb  = rest % KB;
    int nt  = rest / KB;
    int k = (kb << 5) + (kg << 3) + j;
    int col = (nt << 7) + n;
    float v = (k < Kreal) ? W[(size_t)k * N + col] : 0.f;
    short hi = f2bf(v);
    out[e] = (seg == 0) ? hi : f2bf(v - bf2f(hi));
}

// ---- prep: zscore + concat + expmap0 -> bf16, interleaved [kb][hi32|lo32]. Wave-per-row. ----
__global__ __launch_bounds__(256) void prep_kernel(
    const float* __restrict__ s0, const float* __restrict__ s1,
    const float* __restrict__ s2, const float* __restrict__ s3,
    int f0, int f1, int f2, int f3,
    short* __restrict__ Xb, float* __restrict__ xn_out) {
    __shared__ float xbuf[4][1712];
    const int lane = threadIdx.x & 63, wave = threadIdx.x >> 6;
    const int row = blockIdx.x * 4 + wave;
    float* xb = xbuf[wave];
    const float* srcs[4] = {s0, s1, s2, s3};
    const int fs[4] = {f0, f1, f2, f3};
    int off = 0;
    for (int b = 0; b < 4; b++) {
        int F = fs[b];
        if (F == 0) break;
        const float* srow = srcs[b] + (size_t)row * F;
        float ps = 0.f;
        for (int i = lane; i < F; i += 64) { float v = srow[i]; xb[off + i] = v; ps += v; }
        float mean = wsum(ps) / (float)F;
        float pq = 0.f;
        for (int i = lane; i < F; i += 64) { float d = xb[off + i] - mean; pq += d * d; }
        float var = wsum(pq) / (float)(F - 1);
        float inv = 1.0f / (sqrtf(var) + 1e-8f);
        for (int i = lane; i < F; i += 64) xb[off + i] = (xb[off + i] - mean) * inv;
        off += F;
    }
    float pn = 0.f;
    for (int i = lane; i < 1711; i += 64) pn += xb[i] * xb[i];
    float n = fmaxf(sqrtf(wsum(pn)), 1e-15f);
    float t = tanhf(n);
    float sc = t / n;
    short* xrow = Xb + (size_t)row * 3456;   // [kb(54)][hi(32)|lo(32)]
    for (int i = lane; i < 1728; i += 64) {
        float v = (i < 1711) ? sc * xb[i] : 0.f;
        short hi = f2bf(v);
        int base = (i >> 5) * 64 + (i & 31);
        xrow[base] = hi;
        xrow[base + 32] = f2bf(v - bf2f(hi));
    }
    if (lane == 0) xn_out[row] = fmaxf(t, 1e-15f);
}

// ---- bf16 MFMA GEMM, fused 3-term split precision, line-dense A, XCD swizzle ----
// A: bf16 [M][lda], lda = 2*Kpad, layout [kb][hi32|lo32] per row (128B lines).
// Wp packed per pack_w_kernel. Grid: 1D, NT*M/128 blocks, NT = 1<<ntShift.
// T4 counted-vmcnt schedule (depth-2 ring, 2 x 32KB LDS, 2 blocks/CU):
//   prologue stage(T0),stage(T1);
//   iter t: s_waitcnt vmcnt(8)  -- retires tile t (issued one full iter ago)
//           s_barrier            -- tile-t LDS writes visible to all waves
//           compute(buf t&1)     -- ds_read + 48 MFMA
//           s_barrier            -- all reads done, buffer reusable
//           stage(buf t&1 <- T(t+2))
// vmcnt never drains to 0 in the main loop (8 loads/tile/wave: 4 A + 4 B).
// Rounds 3/4 lessons: keep 2 blocks/CU; keep B staged through LDS.
__global__ __launch_bounds__(256) void gemm_mfma(
    const short* __restrict__ A, int lda, int KB,
    const short* __restrict__ Wp,
    float* __restrict__ C, int N, int ntShift) {
    __shared__ short As[2][8192];  // 128 rows x 64 shorts; 16B-unit slot = p ^ (row&7)
    __shared__ short Bs[2][8192];  // [seg(2)][kg(4)][n(128)][j(8)]
    const int tid = threadIdx.x;
    const int lane = tid & 63;
    const int wave = __builtin_amdgcn_readfirstlane(tid >> 6);
    const int waveM = wave >> 1, waveN = wave & 1;
    const int kg = lane >> 4, l16 = lane & 15;

    // XCD-aware swizzle: same m-strip -> same XCD, consecutive in time
    int flat = blockIdx.x;
    int xcd = flat & 7;
    int idx = flat >> 3;
    int q = idx >> ntShift;
    int nt = idx & ((1 << ntShift) - 1);
    int mt = q * 8 + xcd;
    const int m0 = mt * 128;

    f32x4 acc[4][4] = {};
    const short* Bbase = Wp + (size_t)nt * KB * 8192;

    // stage tile kb into ring buffer b: exactly 8 global_load_lds per wave.
    // LDS dest is wave-uniform base (+lane*16B implicit); the A swizzle
    // (unit slot p = (u&7)^(row&7)) lives in the per-lane GLOBAL address.
    auto stage = [&](int b, int kb) {
#pragma unroll
        for (int c = 0; c < 4; c++) {
            int u = c * 256 + wave * 64 + lane;
            int row = u >> 3;
            int p = (u & 7) ^ (row & 7);
            const short* ga = A + (size_t)(m0 + row) * lda + kb * 64 + p * 8;
            __builtin_amdgcn_global_load_lds(
                (const __attribute__((address_space(1))) unsigned int*)ga,
                (__attribute__((address_space(3))) unsigned int*)&As[b][(c * 256 + wave * 64) * 8],
                16, 0, 0);
        }
#pragma unroll
        for (int c = 0; c < 4; c++) {
            int u = c * 256 + wave * 64 + lane;
            const short* gb = Bbase + (size_t)kb * 8192 + u * 8;
            __builtin_amdgcn_global_load_lds(
                (const __attribute__((address_space(1))) unsigned int*)gb,
                (__attribute__((address_space(3))) unsigned int*)&Bs[b][(c * 256 + wave * 64) * 8],
                16, 0, 0);
        }
    };

    auto compute = [&](int cb) {
        bf16x8 ah[4], al[4], bh[4], bl[4];
#pragma unroll
        for (int mi = 0; mi < 4; mi++) {
            int r = waveM * 64 + mi * 16 + l16;
            int uh = r * 8 + (kg ^ (r & 7));
            int ul = r * 8 + ((4 + kg) ^ (r & 7));
            ah[mi] = *(const bf16x8*)&As[cb][uh * 8];
            al[mi] = *(const bf16x8*)&As[cb][ul * 8];
        }
#pragma unroll
        for (int ni = 0; ni < 4; ni++) {
            int n = waveN * 64 + ni * 16 + l16;
            bh[ni] = *(const bf16x8*)&Bs[cb][(kg * 128 + n) * 8];
            bl[ni] = *(const bf16x8*)&Bs[cb][(512 + kg * 128 + n) * 8];
        }
        __builtin_amdgcn_s_setprio(1);
#pragma unroll
        for (int mi = 0; mi < 4; mi++)
#pragma unroll
            for (int ni = 0; ni < 4; ni++)
                acc[mi][ni] = __builtin_amdgcn_mfma_f32_16x16x32_bf16(ah[mi], bh[ni], acc[mi][ni], 0, 0, 0);
#pragma unroll
        for (int mi = 0; mi < 4; mi++)
#pragma unroll
            for (int ni = 0; ni < 4; ni++)
                acc[mi][ni] = __builtin_amdgcn_mfma_f32_16x16x32_bf16(al[mi], bh[ni], acc[mi][ni], 0, 0, 0);
#pragma unroll
        for (int mi = 0; mi < 4; mi++)
#pragma unroll
            for (int ni = 0; ni < 4; ni++)
                acc[mi][ni] = __builtin_amdgcn_mfma_f32_16x16x32_bf16(ah[mi], bl[ni], acc[mi][ni], 0, 0, 0);
        __builtin_amdgcn_s_setprio(0);
    };

    // prologue: two tiles in flight (16 outstanding loads/wave)
    stage(0, 0);
    stage(1, 1);
    for (int t = 0; t < KB; t++) {
        // retire tile t's 8 loads (issued a full iteration ago); keep the
        // newest <=8 (tile t+1) in flight. Never drain to 0 mid-loop.
        if (t < KB - 1) {
            asm volatile("s_waitcnt vmcnt(8)" ::: "memory");
        } else {
            asm volatile("s_waitcnt vmcnt(0)" ::: "memory");
        }
        __builtin_amdgcn_s_barrier();      // tile-t LDS writes visible everywhere
        compute(t & 1);
        __builtin_amdgcn_s_barrier();      // all waves done reading buf[t&1]
        if (t + 2 < KB) stage(t & 1, t + 2);
    }
    const int rbase = m0 + waveM * 64 + (lane >> 4) * 4;
    const int cbase = nt * 128 + waveN * 64 + l16;
#pragma unroll
    for (int mi = 0; mi < 4; mi++)
#pragma unroll
        for (int ni = 0; ni < 4; ni++)
#pragma unroll
            for (int r = 0; r < 4; r++)
                C[(size_t)(rbase + mi * 16 + r) * N + cbase + ni * 16] = acc[mi][ni][r];
}

// ---- hyperbolic linear head, wave-level, E elements per lane (zero-filled if inactive) ----
template<int E>
__device__ float hyper_head_w(float (&v)[E], const float (&bv)[E], float xn, int do_tanh) {
    float p = 0.f;
#pragma unroll
    for (int e = 0; e < E; e++) p += v[e] * v[e];
    float mxn = fmaxf(sqrtf(wsum(p)), 1e-15f);
    float t1 = tanhf((mxn / xn) * artanh_c(xn));
    float ny = fmaxf(t1, 1e-15f);
    float fac = (ny > MAXNORM_F) ? (MAXNORM_F / ny) : 1.0f;
    float sm = t1 * fac / mxn;
    float pa2 = 0.f, pab = 0.f, pb2 = 0.f;
#pragma unroll
    for (int e = 0; e < E; e++) {
        v[e] *= sm;
        pa2 += v[e] * v[e]; pab += v[e] * bv[e]; pb2 += bv[e] * bv[e];
    }
    float a2 = wsum(pa2);
    float ab = wsum(pab);
    float b2 = wsum(pb2);
    float den = fmaxf(1.0f + 2.0f * ab + a2 * b2, 1e-15f);
    float ca = (1.0f + 2.0f * ab + b2) / den;
    float cb = (1.0f - a2) / den;
    float pz2 = 0.f;
#pragma unroll
    for (int e = 0; e < E; e++) {
        v[e] = ca * v[e] + cb * bv[e];
        pz2 += v[e] * v[e];
    }
    float nz = fmaxf(sqrtf(wsum(pz2)), 1e-15f);
    float fz = (nz > MAXNORM_F) ? (MAXNORM_F / nz) : 1.0f;
    float nzp = nz * fz;
    if (!do_tanh) {
#pragma unroll
        for (int e = 0; e < E; e++) v[e] *= fz;
        return nzp;
    }
    float ia = artanh_c(nzp) / nzp * fz;
    float pt2 = 0.f;
#pragma unroll
    for (int e = 0; e < E; e++) {
        v[e] = tanhf(ia * v[e]);
        pt2 += v[e] * v[e];
    }
    float ntn = fmaxf(sqrtf(wsum(pt2)), 1e-15f);
    float to = tanhf(ntn);
    float no = fmaxf(to, 1e-15f);
    float fo = (no > MAXNORM_F) ? (MAXNORM_F / no) : 1.0f;
    float so = to / ntn * fo;
#pragma unroll
    for (int e = 0; e < E; e++) v[e] *= so;
    return fminf(no, MAXNORM_F);
}

// ---- epilogue: wave-per-row, 4 rows/block. N = VPT*256. Writes interleaved [kb][hi|lo]. ----
template<int VPT>
__global__ __launch_bounds__(256) void epi_kernel(
    const float* __restrict__ MX, int N, const float* __restrict__ bias,
    float* __restrict__ xn_io, short* __restrict__ Xout, int ldx,
    float* __restrict__ Fout, int do_tanh) {
    const int lane = threadIdx.x & 63, wave = threadIdx.x >> 6;
    const int row = blockIdx.x * 4 + wave;
    const float* mrow = MX + (size_t)row * N;
    float v[4 * VPT], bv[4 * VPT];
#pragma unroll
    for (int j = 0; j < VPT; j++) {
        int idx = j * 256 + lane * 4;
        float4 t = *(const float4*)(mrow + idx);
        v[4 * j] = t.x; v[4 * j + 1] = t.y; v[4 * j + 2] = t.z; v[4 * j + 3] = t.w;
        float4 tb = *(const float4*)(bias + idx);
        bv[4 * j] = tb.x; bv[4 * j + 1] = tb.y; bv[4 * j + 2] = tb.z; bv[4 * j + 3] = tb.w;
    }
    float xn = xn_io[row];
    float nrm = hyper_head_w<4 * VPT>(v, bv, xn, do_tanh);
    if (Xout) {
        short* orow = Xout + (size_t)row * ldx;
#pragma unroll
        for (int j = 0; j < VPT; j++) {
            int idx = j * 256 + lane * 4;
            int base = (idx >> 5) * 64 + (idx & 31);
            short4 h4, l4;
            short hi;
            hi = f2bf(v[4 * j + 0]); h4.x = hi; l4.x = f2bf(v[4 * j + 0] - bf2f(hi));
            hi = f2bf(v[4 * j + 1]); h4.y = hi; l4.y = f2bf(v[4 * j + 1] - bf2f(hi));
            hi = f2bf(v[4 * j + 2]); h4.z = hi; l4.z = f2bf(v[4 * j + 2] - bf2f(hi));
            hi = f2bf(v[4 * j + 3]); h4.w = hi; l4.w = f2bf(v[4 * j + 3] - bf2f(hi));
            *(short4*)(orow + base) = h4;
            *(short4*)(orow + base + 32) = l4;
        }
    }
    if (Fout) {
        float* orow = Fout + (size_t)row * N;
#pragma unroll
        for (int j = 0; j < VPT; j++) {
            int idx = j * 256 + lane * 4;
            float4 t;
            t.x = v[4 * j]; t.y = v[4 * j + 1]; t.z = v[4 * j + 2]; t.w = v[4 * j + 3];
            *(float4*)(orow + idx) = t;
        }
    }
    if (lane == 0) xn_io[row] = fmaxf(nrm, 1e-15f);
}

// ---- merge + 3-layer Mobius MLP, wave-per-row ----
__global__ __launch_bounds__(256) void merge_mlp_kernel(
    const float* __restrict__ head, const float* __restrict__ tail,
    const float* __restrict__ nh_arr, const float* __restrict__ nt_arr,
    const float* __restrict__ Wm1, const float* __restrict__ bm1,
    const float* __restrict__ Wm2, const float* __restrict__ bm2,
    const float* __restrict__ Wm3, const float* __restrict__ bm3,
    float* __restrict__ out) {
    __shared__ float xs[4][256];
    const int lane = threadIdx.x & 63, wave = threadIdx.x >> 6;
    const int row = blockIdx.x * 4 + wave;
    float* x = xs[wave];
    float4 h4 = *(const float4*)(head + (size_t)row * 256 + lane * 4);
    float4 t4 = *(const float4*)(tail + (size_t)row * 256 + lane * 4);
    float A[4] = {h4.x, h4.y, h4.z, h4.w};
    float Bv[4] = {t4.x, t4.y, t4.z, t4.w};
    float nh = nh_arr[row], ntl = nt_arr[row];
    float sh = tanhf(0.27f * artanh_c(nh)) / nh;
    float st = tanhf(0.73f * artanh_c(ntl)) / ntl;
    float px2 = 0.f, py2 = 0.f, pxy = 0.f;
#pragma unroll
    for (int e = 0; e < 4; e++) {
        A[e] *= sh; Bv[e] *= st;
        px2 += A[e] * A[e]; py2 += Bv[e] * Bv[e]; pxy += A[e] * Bv[e];
    }
    float x2 = wsum(px2), y2 = wsum(py2), xy = wsum(pxy);
    float den = fmaxf(1.0f + 2.0f * xy + x2 * y2, 1e-15f);
    float ca = (1.0f + 2.0f * xy + y2) / den, cb = (1.0f - x2) / den;
    float z[4]; float pz2 = 0.f;
#pragma unroll
    for (int e = 0; e < 4; e++) { z[e] = ca * A[e] + cb * Bv[e]; pz2 += z[e] * z[e]; }
    float nz = fmaxf(sqrtf(wsum(pz2)), 1e-15f);
    float fz = (nz > MAXNORM_F) ? (MAXNORM_F / nz) : 1.0f;
    float nmid = nz * fz;
    float4 zs; zs.x = z[0] * fz; zs.y = z[1] * fz; zs.z = z[2] * fz; zs.w = z[3] * fz;
    *(float4*)(x + lane * 4) = zs;

    float v[1], bvv[1];
    {
        float acc = 0.f;
        for (int k = 0; k < 256; k++) acc += x[k] * Wm1[k * 64 + lane];
        v[0] = acc; bvv[0] = bm1[lane];
    }
    float n1 = hyper_head_w<1>(v, bvv, nmid, 1);
    x[lane] = v[0];
    {
        float acc = 0.f;
        if (lane < 32) { for (int k = 0; k < 64; k++) acc += x[k] * Wm2[k * 32 + lane]; }
        v[0] = (lane < 32) ? acc : 0.f;
        bvv[0] = (lane < 32) ? bm2[lane] : 0.f;
    }
    float n2 = hyper_head_w<1>(v, bvv, n1, 1);
    x[lane] = (lane < 32) ? v[0] : 0.f;
    {
        float acc = 0.f;
        if (lane < 2) { for (int k = 0; k < 32; k++) acc += x[k] * Wm3[k * 2 + lane]; }
        v[0] = (lane < 2) ? acc : 0.f;
        bvv[0] = (lane < 2) ? bm3[lane] : 0.f;
    }
    hyper_head_w<1>(v, bvv, n2, 0);
    if (lane < 2) out[(size_t)row * 2 + lane] = v[0];
}

// ---- launch ----
extern "C" void kernel_launch(void* const* d_in, const int* in_sizes, int n_in,
                              void* d_out, int out_size, void* d_ws, size_t ws_size,
                              hipStream_t stream) {
    const float* dch = (const float*)d_in[0];
    const float* dpc = (const float*)d_in[1];
    const float* dmc = (const float*)d_in[2];
    const float* dec = (const float*)d_in[3];
    const float* tes = (const float*)d_in[4];
    const float* tpc = (const float*)d_in[5];
    const float* tme = (const float*)d_in[6];
    const float* Wd1 = (const float*)d_in[7];  const float* bd1 = (const float*)d_in[8];
    const float* Wd2 = (const float*)d_in[9];  const float* bd2 = (const float*)d_in[10];
    const float* Wd3 = (const float*)d_in[11]; const float* bd3 = (const float*)d_in[12];
    const float* Wt1 = (const float*)d_in[13]; const float* bt1 = (const float*)d_in[14];
    const float* Wt2 = (const float*)d_in[15]; const float* bt2 = (const float*)d_in[16];
    const float* Wt3 = (const float*)d_in[17]; const float* bt3 = (const float*)d_in[18];
    const float* Wm1 = (const float*)d_in[19]; const float* bm1 = (const float*)d_in[20];
    const float* Wm2 = (const float*)d_in[21]; const float* bm2 = (const float*)d_in[22];
    const float* Wm3 = (const float*)d_in[23]; const float* bm3 = (const float*)d_in[24];

    const int B = in_sizes[0] / 768;   // 16384

    float* mx  = (float*)d_ws;                          // B*1024 f32
    short* xb  = (short*)(mx + (size_t)B * 1024);       // B*3456 bf16 (shared both branches)
    float* hf_d = (float*)(xb + (size_t)B * 3456);      // B*256 f32
    float* hf_t = hf_d + (size_t)B * 256;
    float* xn_d = hf_t + (size_t)B * 256;
    float* xn_t = xn_d + B;
    // packed weights: [ntile][KB][2][4096] shorts
    short* wp_d1 = (short*)(xn_t + B);                  // 8*54*8192
    short* wp_d2 = wp_d1 + 8 * 54 * 8192;               // 4*32*8192
    short* wp_d3 = wp_d2 + 4 * 32 * 8192;               // 2*16*8192
    short* wp_t1 = wp_d3 + 2 * 16 * 8192;
    short* wp_t2 = wp_t1 + 8 * 54 * 8192;
    short* wp_t3 = wp_t2 + 4 * 32 * 8192;

    dim3 blk(256);
    int e1 = 8 * 54 * 8192, e2 = 4 * 32 * 8192, e3 = 2 * 16 * 8192;
    hipLaunchKernelGGL(pack_w_kernel, dim3((e1 + 255) / 256), blk, 0, stream, Wd1, 1711, 54, 1024, wp_d1);
    hipLaunchKernelGGL(pack_w_kernel, dim3((e2 + 255) / 256), blk, 0, stream, Wd2, 1024, 32, 512, wp_d2);
    hipLaunchKernelGGL(pack_w_kernel, dim3((e3 + 255) / 256), blk, 0, stream, Wd3, 512, 16, 256, wp_d3);
    hipLaunchKernelGGL(pack_w_kernel, dim3((e1 + 255) / 256), blk, 0, stream, Wt1, 1711, 54, 1024, wp_t1);
    hipLaunchKernelGGL(pack_w_kernel, dim3((e2 + 255) / 256), blk, 0, stream, Wt2, 1024, 32, 512, wp_t2);
    hipLaunchKernelGGL(pack_w_kernel, dim3((e3 + 255) / 256), blk, 0, stream, Wt3, 512, 16, 256, wp_t3);

    // ---- drug branch ----
    hipLaunchKernelGGL(prep_kernel, dim3(B / 4), blk, 0, stream,
                       dch, dpc, dmc, dec, 768, 11, 167, 765, xb, xn_d);
    hipLaunchKernelGGL(gemm_mfma, dim3(8 * (B / 128)), blk, 0, stream, xb, 3456, 54, wp_d1, mx, 1024, 3);
    hipLaunchKernelGGL((epi_kernel<4>), dim3(B / 4), blk, 0, stream, mx, 1024, bd1, xn_d, xb, 2048, (float*)nullptr, 1);
    hipLaunchKernelGGL(gemm_mfma, dim3(4 * (B / 128)), blk, 0, stream, xb, 2048, 32, wp_d2, mx, 512, 2);
    hipLaunchKernelGGL((epi_kernel<2>), dim3(B / 4), blk, 0, stream, mx, 512, bd2, xn_d, xb, 1024, (float*)nullptr, 1);
    hipLaunchKernelGGL(gemm_mfma, dim3(2 * (B / 128)), blk, 0, stream, xb, 1024, 16, wp_d3, mx, 256, 1);
    hipLaunchKernelGGL((epi_kernel<1>), dim3(B / 4), blk, 0, stream, mx, 256, bd3, xn_d, (short*)nullptr, 0, hf_d, 0);

    // ---- target branch (reuses xb, mx) ----
    hipLaunchKernelGGL(prep_kernel, dim3(B / 4), blk, 0, stream,
                       tes, tpc, tme, (const float*)nullptr, 1280, 11, 420, 0, xb, xn_t);
    hipLaunchKernelGGL(gemm_mfma, dim3(8 * (B / 128)), blk, 0, stream, xb, 3456, 54, wp_t1, mx, 1024, 3);
    hipLaunchKernelGGL((epi_kernel<4>), dim3(B / 4), blk, 0, stream, mx, 1024, bt1, xn_t, xb, 2048, (float*)nullptr, 1);
    hipLaunchKernelGGL(gemm_mfma, dim3(4 * (B / 128)), blk, 0, stream, xb, 2048, 32, wp_t2, mx, 512, 2);
    hipLaunchKernelGGL((epi_kernel<2>), dim3(B / 4), blk, 0, stream, mx, 512, bt2, xn_t, xb, 1024, (float*)nullptr, 1);
    hipLaunchKernelGGL(gemm_mfma, dim3(2 * (B / 128)), blk, 0, stream, xb, 1024, 16, wp_t3, mx, 256, 1);
    hipLaunchKernelGGL((epi_kernel<1>), dim3(B / 4), blk, 0, stream, mx, 256, bt3, xn_t, (short*)nullptr, 0, hf_t, 0);

    // ---- merge + MLP -> out ----
    hipLaunchKernelGGL(merge_mlp_kernel, dim3(B / 4), blk, 0, stream,
                       hf_d, hf_t, xn_d, xn_t, Wm1, bm1, Wm2, bm2, Wm3, bm3, (float*)d_out);
}

// Round 6
// 900.818 us; speedup vs baseline: 1.2104x; 1.1520x over previous
//
#include <hip/hip_runtime.h>
#include <math.h>

#define MAXNORM_F 0.996f

typedef __attribute__((ext_vector_type(8))) short bf16x8;
typedef __attribute__((ext_vector_type(4))) float f32x4;

__device__ __forceinline__ short f2bf(float f) {
    union { float f; unsigned u; } v; v.f = f;
    unsigned r = v.u + 0x7FFF + ((v.u >> 16) & 1);
    return (short)(r >> 16);
}
__device__ __forceinline__ float bf2f(short s) {
    union { unsigned u; float f; } v; v.u = ((unsigned)(unsigned short)s) << 16;
    return v.f;
}

__device__ __forceinline__ float artanh_c(float x) {
    const float lim = 1.0f - 1e-5f;
    x = fminf(fmaxf(x, -lim), lim);
    return 0.5f * logf((1.0f + x) / (1.0f - x));
}

// full 64-lane wave sum, result in all lanes
__device__ __forceinline__ float wsum(float v) {
#pragma unroll
    for (int m = 32; m > 0; m >>= 1) v += __shfl_xor(v, m, 64);
    return v;
}

// ---- weight pack body: fp32 [K][N] -> bf16 [ntile][kb][seg(2:hi,lo)][kg(4)][n(128)][j(8)] ----
__device__ __forceinline__ void pack_body(
    const float* __restrict__ W, int Kreal, int KB, int N, short* __restrict__ out, int e) {
    int total = (N >> 7) * KB * 2 * 4096;
    if (e >= total) return;
    int j   = e & 7;
    int n   = (e >> 3) & 127;
    int kg  = (e >> 10) & 3;
    int seg = (e >> 12) & 1;
    int rest = e >> 13;
    int kb  = rest % KB;
    int nt  = rest / KB;
    int k = (kb << 5) + (kg << 3) + j;
    int col = (nt << 7) + n;
    float v = (k < Kreal) ? W[(size_t)k * N + col] : 0.f;
    short hi = f2bf(v);
    out[e] = (seg == 0) ? hi : f2bf(v - bf2f(hi));
}

// fused pack of all 6 weight matrices in ONE launch (block-range dispatch).
// Grid = 2*(13824+4096+1024) = 37888 blocks of 256.
__global__ __launch_bounds__(256) void pack_all_kernel(
    const float* __restrict__ Wd1, short* __restrict__ o1,
    const float* __restrict__ Wd2, short* __restrict__ o2,
    const float* __restrict__ Wd3, short* __restrict__ o3,
    const float* __restrict__ Wt1, short* __restrict__ o4,
    const float* __restrict__ Wt2, short* __restrict__ o5,
    const float* __restrict__ Wt3, short* __restrict__ o6) {
    int b = blockIdx.x;
    const int tid = threadIdx.x;
    const int B1 = 13824, B2 = 4096, B3 = 1024;   // e1/256, e2/256, e3/256
    if (b < B1)              { pack_body(Wd1, 1711, 54, 1024, o1, b * 256 + tid); return; }
    b -= B1;
    if (b < B2)              { pack_body(Wd2, 1024, 32,  512, o2, b * 256 + tid); return; }
    b -= B2;
    if (b < B3)              { pack_body(Wd3,  512, 16,  256, o3, b * 256 + tid); return; }
    b -= B3;
    if (b < B1)              { pack_body(Wt1, 1711, 54, 1024, o4, b * 256 + tid); return; }
    b -= B1;
    if (b < B2)              { pack_body(Wt2, 1024, 32,  512, o5, b * 256 + tid); return; }
    b -= B2;
    pack_body(Wt3, 512, 16, 256, o6, b * 256 + tid);
}

// ---- prep: zscore + concat + expmap0 -> bf16, interleaved [kb][hi32|lo32]. Wave-per-row. ----
// G13: global loads vectorized float4 (alignment-corrected per row via scalar
// head/tail; vector body is guaranteed 16B-aligned); output pass uses f32x4
// LDS reads + short4 x2 global stores.
__global__ __launch_bounds__(256) void prep_kernel(
    const float* __restrict__ s0, const float* __restrict__ s1,
    const float* __restrict__ s2, const float* __restrict__ s3,
    int f0, int f1, int f2, int f3,
    short* __restrict__ Xb, float* __restrict__ xn_out) {
    __shared__ __align__(16) float xbuf[4][1712];
    const int lane = threadIdx.x & 63, wave = threadIdx.x >> 6;
    const int row = blockIdx.x * 4 + wave;
    float* xb = xbuf[wave];
    const float* srcs[4] = {s0, s1, s2, s3};
    const int fs[4] = {f0, f1, f2, f3};
    int off = 0;
    for (int b = 0; b < 4; b++) {
        int F = fs[b];
        if (F == 0) break;
        const float* srow = srcs[b] + (size_t)row * F;
        // element misalignment of this row vs 16B (srcs base is >=256B aligned)
        int mis = (int)(((size_t)row * (size_t)F) & 3);
        int s = (4 - mis) & 3; if (s > F) s = F;
        float ps = 0.f;
        if (lane < s) { float v = srow[lane]; xb[off + lane] = v; ps += v; }
        for (int base = s + lane * 4; base + 3 < F; base += 256) {
            f32x4 v = *(const f32x4*)(srow + base);   // 16B-aligned by construction
            xb[off + base] = v.x; xb[off + base + 1] = v.y;
            xb[off + base + 2] = v.z; xb[off + base + 3] = v.w;
            ps += v.x + v.y + v.z + v.w;
        }
        int ti = s + ((F - s) & ~3) + lane;
        if (ti < F) { float v = srow[ti]; xb[off + ti] = v; ps += v; }

        float mean = wsum(ps) / (float)F;
        float pq = 0.f;
        for (int i = lane; i < F; i += 64) { float d = xb[off + i] - mean; pq += d * d; }
        float var = wsum(pq) / (float)(F - 1);
        float inv = 1.0f / (sqrtf(var) + 1e-8f);
        for (int i = lane; i < F; i += 64) xb[off + i] = (xb[off + i] - mean) * inv;
        off += F;
    }
    // row norm over [0,1711): vectorized groups of 4 (xb 16B-aligned, i%4==0)
    float pn = 0.f;
#pragma unroll
    for (int j = 0; j < 7; j++) {
        int i = j * 256 + lane * 4;
        if (i >= 1712) continue;
        if (i + 3 < 1711) {
            f32x4 t = *(const f32x4*)&xb[i];
            pn += t.x * t.x + t.y * t.y + t.z * t.z + t.w * t.w;
        } else {
#pragma unroll
            for (int k = 0; k < 4; k++) if (i + k < 1711) pn += xb[i + k] * xb[i + k];
        }
    }
    float n = fmaxf(sqrtf(wsum(pn)), 1e-15f);
    float t = tanhf(n);
    float sc = t / n;
    short* xrow = Xb + (size_t)row * 3456;   // [kb(54)][hi(32)|lo(32)]
#pragma unroll
    for (int j = 0; j < 7; j++) {
        int i = j * 256 + lane * 4;
        if (i >= 1728) continue;
        float v0, v1, v2, v3;
        if (i + 3 < 1711) {
            f32x4 tv = *(const f32x4*)&xb[i];
            v0 = sc * tv.x; v1 = sc * tv.y; v2 = sc * tv.z; v3 = sc * tv.w;
        } else {
            v0 = (i + 0 < 1711) ? sc * xb[i + 0] : 0.f;
            v1 = (i + 1 < 1711) ? sc * xb[i + 1] : 0.f;
            v2 = (i + 2 < 1711) ? sc * xb[i + 2] : 0.f;
            v3 = (i + 3 < 1711) ? sc * xb[i + 3] : 0.f;
        }
        short4 h4, l4;
        short hi;
        hi = f2bf(v0); h4.x = hi; l4.x = f2bf(v0 - bf2f(hi));
        hi = f2bf(v1); h4.y = hi; l4.y = f2bf(v1 - bf2f(hi));
        hi = f2bf(v2); h4.z = hi; l4.z = f2bf(v2 - bf2f(hi));
        hi = f2bf(v3); h4.w = hi; l4.w = f2bf(v3 - bf2f(hi));
        int base = (i >> 5) * 64 + (i & 31);   // i%4==0 -> short4 8B-aligned
        *(short4*)(xrow + base) = h4;
        *(short4*)(xrow + base + 32) = l4;
    }
    if (lane == 0) xn_out[row] = fmaxf(t, 1e-15f);
}

// ---- bf16 MFMA GEMM, fused 3-term split precision, line-dense A, XCD swizzle ----
// A: bf16 [M][lda], lda = 2*Kpad, layout [kb][hi32|lo32] per row (128B lines).
// Wp packed per pack. Grid: 1D, NT*M/128 blocks, NT = 1<<ntShift.
// R1 winner structure: depth-1 prefetch (stage next BEFORE compute), single
// __syncthreads per iteration, 2x32KB LDS -> 2 blocks/CU. R3/R4/R5 all lost:
// 1 blk/CU, B-bypass, counted-vmcnt+2-barrier each worse than this.
__global__ __launch_bounds__(256) void gemm_mfma(
    const short* __restrict__ A, int lda, int KB,
    const short* __restrict__ Wp,
    float* __restrict__ C, int N, int ntShift) {
    __shared__ short As[2][8192];  // 128 rows x 64 shorts; 16B-unit slot = p ^ (row&7)
    __shared__ short Bs[2][8192];  // [seg(2)][kg(4)][n(128)][j(8)]
    const int tid = threadIdx.x;
    const int lane = tid & 63;
    const int wave = __builtin_amdgcn_readfirstlane(tid >> 6);
    const int waveM = wave >> 1, waveN = wave & 1;
    const int kg = lane >> 4, l16 = lane & 15;

    // XCD-aware swizzle: same m-strip -> same XCD, consecutive in time
    int flat = blockIdx.x;
    int xcd = flat & 7;
    int idx = flat >> 3;
    int q = idx >> ntShift;
    int nt = idx & ((1 << ntShift) - 1);
    int mt = q * 8 + xcd;
    const int m0 = mt * 128;

    f32x4 acc[4][4] = {};
    const short* Bbase = Wp + (size_t)nt * KB * 8192;

    // stage one K-tile into buffer b. LDS dest is wave-uniform base (+lane*16B
    // implicit); the A swizzle (unit slot p = (u&7)^(row&7)) lives in the
    // per-lane GLOBAL address (pre-swizzled-source pattern).
    auto stage = [&](int b, int kb) {
#pragma unroll
        for (int c = 0; c < 4; c++) {
            int u = c * 256 + wave * 64 + lane;
            int row = u >> 3;
            int p = (u & 7) ^ (row & 7);
            const short* ga = A + (size_t)(m0 + row) * lda + kb * 64 + p * 8;
            __builtin_amdgcn_global_load_lds(
                (const __attribute__((address_space(1))) unsigned int*)ga,
                (__attribute__((address_space(3))) unsigned int*)&As[b][(c * 256 + wave * 64) * 8],
                16, 0, 0);
        }
#pragma unroll
        for (int c = 0; c < 4; c++) {
            int u = c * 256 + wave * 64 + lane;
            const short* gb = Bbase + (size_t)kb * 8192 + u * 8;
            __builtin_amdgcn_global_load_lds(
                (const __attribute__((address_space(1))) unsigned int*)gb,
                (__attribute__((address_space(3))) unsigned int*)&Bs[b][(c * 256 + wave * 64) * 8],
                16, 0, 0);
        }
    };

    stage(0, 0);
    __syncthreads();
    int cur = 0;
    for (int kb = 0; kb < KB; kb++) {
        if (kb + 1 < KB) stage(cur ^ 1, kb + 1);  // prefetch flies during MFMA below
        bf16x8 ah[4], al[4], bh[4], bl[4];
#pragma unroll
        for (int mi = 0; mi < 4; mi++) {
            int r = waveM * 64 + mi * 16 + l16;
            int uh = r * 8 + (kg ^ (r & 7));
            int ul = r * 8 + ((4 + kg) ^ (r & 7));
            ah[mi] = *(const bf16x8*)&As[cur][uh * 8];
            al[mi] = *(const bf16x8*)&As[cur][ul * 8];
        }
#pragma unroll
        for (int ni = 0; ni < 4; ni++) {
            int n = waveN * 64 + ni * 16 + l16;
            bh[ni] = *(const bf16x8*)&Bs[cur][(kg * 128 + n) * 8];
            bl[ni] = *(const bf16x8*)&Bs[cur][(512 + kg * 128 + n) * 8];
        }
        __builtin_amdgcn_s_setprio(1);
#pragma unroll
        for (int mi = 0; mi < 4; mi++)
#pragma unroll
            for (int ni = 0; ni < 4; ni++)
                acc[mi][ni] = __builtin_amdgcn_mfma_f32_16x16x32_bf16(ah[mi], bh[ni], acc[mi][ni], 0, 0, 0);
#pragma unroll
        for (int mi = 0; mi < 4; mi++)
#pragma unroll
            for (int ni = 0; ni < 4; ni++)
                acc[mi][ni] = __builtin_amdgcn_mfma_f32_16x16x32_bf16(al[mi], bh[ni], acc[mi][ni], 0, 0, 0);
#pragma unroll
        for (int mi = 0; mi < 4; mi++)
#pragma unroll
            for (int ni = 0; ni < 4; ni++)
                acc[mi][ni] = __builtin_amdgcn_mfma_f32_16x16x32_bf16(ah[mi], bl[ni], acc[mi][ni], 0, 0, 0);
        __builtin_amdgcn_s_setprio(0);
        __syncthreads();   // drains vmcnt(0)+lgkmcnt(0): next buffer staged, cur fully read
        cur ^= 1;
    }
    const int rbase = m0 + waveM * 64 + (lane >> 4) * 4;
    const int cbase = nt * 128 + waveN * 64 + l16;
#pragma unroll
    for (int mi = 0; mi < 4; mi++)
#pragma unroll
        for (int ni = 0; ni < 4; ni++)
#pragma unroll
            for (int r = 0; r < 4; r++)
                C[(size_t)(rbase + mi * 16 + r) * N + cbase + ni * 16] = acc[mi][ni][r];
}

// ---- hyperbolic linear head, wave-level, E elements per lane (zero-filled if inactive) ----
template<int E>
__device__ float hyper_head_w(float (&v)[E], const float (&bv)[E], float xn, int do_tanh) {
    float p = 0.f;
#pragma unroll
    for (int e = 0; e < E; e++) p += v[e] * v[e];
    float mxn = fmaxf(sqrtf(wsum(p)), 1e-15f);
    float t1 = tanhf((mxn / xn) * artanh_c(xn));
    float ny = fmaxf(t1, 1e-15f);
    float fac = (ny > MAXNORM_F) ? (MAXNORM_F / ny) : 1.0f;
    float sm = t1 * fac / mxn;
    float pa2 = 0.f, pab = 0.f, pb2 = 0.f;
#pragma unroll
    for (int e = 0; e < E; e++) {
        v[e] *= sm;
        pa2 += v[e] * v[e]; pab += v[e] * bv[e]; pb2 += bv[e] * bv[e];
    }
    float a2 = wsum(pa2);
    float ab = wsum(pab);
    float b2 = wsum(pb2);
    float den = fmaxf(1.0f + 2.0f * ab + a2 * b2, 1e-15f);
    float ca = (1.0f + 2.0f * ab + b2) / den;
    float cb = (1.0f - a2) / den;
    float pz2 = 0.f;
#pragma unroll
    for (int e = 0; e < E; e++) {
        v[e] = ca * v[e] + cb * bv[e];
        pz2 += v[e] * v[e];
    }
    float nz = fmaxf(sqrtf(wsum(pz2)), 1e-15f);
    float fz = (nz > MAXNORM_F) ? (MAXNORM_F / nz) : 1.0f;
    float nzp = nz * fz;
    if (!do_tanh) {
#pragma unroll
        for (int e = 0; e < E; e++) v[e] *= fz;
        return nzp;
    }
    float ia = artanh_c(nzp) / nzp * fz;
    float pt2 = 0.f;
#pragma unroll
    for (int e = 0; e < E; e++) {
        v[e] = tanhf(ia * v[e]);
        pt2 += v[e] * v[e];
    }
    float ntn = fmaxf(sqrtf(wsum(pt2)), 1e-15f);
    float to = tanhf(ntn);
    float no = fmaxf(to, 1e-15f);
    float fo = (no > MAXNORM_F) ? (MAXNORM_F / no) : 1.0f;
    float so = to / ntn * fo;
#pragma unroll
    for (int e = 0; e < E; e++) v[e] *= so;
    return fminf(no, MAXNORM_F);
}

// ---- epilogue: wave-per-row, 4 rows/block. N = VPT*256. Writes interleaved [kb][hi|lo]. ----
template<int VPT>
__global__ __launch_bounds__(256) void epi_kernel(
    const float* __restrict__ MX, int N, const float* __restrict__ bias,
    float* __restrict__ xn_io, short* __restrict__ Xout, int ldx,
    float* __restrict__ Fout, int do_tanh) {
    const int lane = threadIdx.x & 63, wave = threadIdx.x >> 6;
    const int row = blockIdx.x * 4 + wave;
    const float* mrow = MX + (size_t)row * N;
    float v[4 * VPT], bv[4 * VPT];
#pragma unroll
    for (int j = 0; j < VPT; j++) {
        int idx = j * 256 + lane * 4;
        float4 t = *(const float4*)(mrow + idx);
        v[4 * j] = t.x; v[4 * j + 1] = t.y; v[4 * j + 2] = t.z; v[4 * j + 3] = t.w;
        float4 tb = *(const float4*)(bias + idx);
        bv[4 * j] = tb.x; bv[4 * j + 1] = tb.y; bv[4 * j + 2] = tb.z; bv[4 * j + 3] = tb.w;
    }
    float xn = xn_io[row];
    float nrm = hyper_head_w<4 * VPT>(v, bv, xn, do_tanh);
    if (Xout) {
        short* orow = Xout + (size_t)row * ldx;
#pragma unroll
        for (int j = 0; j < VPT; j++) {
            int idx = j * 256 + lane * 4;
            int base = (idx >> 5) * 64 + (idx & 31);
            short4 h4, l4;
            short hi;
            hi = f2bf(v[4 * j + 0]); h4.x = hi; l4.x = f2bf(v[4 * j + 0] - bf2f(hi));
            hi = f2bf(v[4 * j + 1]); h4.y = hi; l4.y = f2bf(v[4 * j + 1] - bf2f(hi));
            hi = f2bf(v[4 * j + 2]); h4.z = hi; l4.z = f2bf(v[4 * j + 2] - bf2f(hi));
            hi = f2bf(v[4 * j + 3]); h4.w = hi; l4.w = f2bf(v[4 * j + 3] - bf2f(hi));
            *(short4*)(orow + base) = h4;
            *(short4*)(orow + base + 32) = l4;
        }
    }
    if (Fout) {
        float* orow = Fout + (size_t)row * N;
#pragma unroll
        for (int j = 0; j < VPT; j++) {
            int idx = j * 256 + lane * 4;
            float4 t;
            t.x = v[4 * j]; t.y = v[4 * j + 1]; t.z = v[4 * j + 2]; t.w = v[4 * j + 3];
            *(float4*)(orow + idx) = t;
        }
    }
    if (lane == 0) xn_io[row] = fmaxf(nrm, 1e-15f);
}

// ---- merge + 3-layer Mobius MLP, wave-per-row ----
__global__ __launch_bounds__(256) void merge_mlp_kernel(
    const float* __restrict__ head, const float* __restrict__ tail,
    const float* __restrict__ nh_arr, const float* __restrict__ nt_arr,
    const float* __restrict__ Wm1, const float* __restrict__ bm1,
    const float* __restrict__ Wm2, const float* __restrict__ bm2,
    const float* __restrict__ Wm3, const float* __restrict__ bm3,
    float* __restrict__ out) {
    __shared__ float xs[4][256];
    const int lane = threadIdx.x & 63, wave = threadIdx.x >> 6;
    const int row = blockIdx.x * 4 + wave;
    float* x = xs[wave];
    float4 h4 = *(const float4*)(head + (size_t)row * 256 + lane * 4);
    float4 t4 = *(const float4*)(tail + (size_t)row * 256 + lane * 4);
    float A[4] = {h4.x, h4.y, h4.z, h4.w};
    float Bv[4] = {t4.x, t4.y, t4.z, t4.w};
    float nh = nh_arr[row], ntl = nt_arr[row];
    float sh = tanhf(0.27f * artanh_c(nh)) / nh;
    float st = tanhf(0.73f * artanh_c(ntl)) / ntl;
    float px2 = 0.f, py2 = 0.f, pxy = 0.f;
#pragma unroll
    for (int e = 0; e < 4; e++) {
        A[e] *= sh; Bv[e] *= st;
        px2 += A[e] * A[e]; py2 += Bv[e] * Bv[e]; pxy += A[e] * Bv[e];
    }
    float x2 = wsum(px2), y2 = wsum(py2), xy = wsum(pxy);
    float den = fmaxf(1.0f + 2.0f * xy + x2 * y2, 1e-15f);
    float ca = (1.0f + 2.0f * xy + y2) / den, cb = (1.0f - x2) / den;
    float z[4]; float pz2 = 0.f;
#pragma unroll
    for (int e = 0; e < 4; e++) { z[e] = ca * A[e] + cb * Bv[e]; pz2 += z[e] * z[e]; }
    float nz = fmaxf(sqrtf(wsum(pz2)), 1e-15f);
    float fz = (nz > MAXNORM_F) ? (MAXNORM_F / nz) : 1.0f;
    float nmid = nz * fz;
    float4 zs; zs.x = z[0] * fz; zs.y = z[1] * fz; zs.z = z[2] * fz; zs.w = z[3] * fz;
    *(float4*)(x + lane * 4) = zs;

    float v[1], bvv[1];
    {
        float acc = 0.f;
        for (int k = 0; k < 256; k++) acc += x[k] * Wm1[k * 64 + lane];
        v[0] = acc; bvv[0] = bm1[lane];
    }
    float n1 = hyper_head_w<1>(v, bvv, nmid, 1);
    x[lane] = v[0];
    {
        float acc = 0.f;
        if (lane < 32) { for (int k = 0; k < 64; k++) acc += x[k] * Wm2[k * 32 + lane]; }
        v[0] = (lane < 32) ? acc : 0.f;
        bvv[0] = (lane < 32) ? bm2[lane] : 0.f;
    }
    float n2 = hyper_head_w<1>(v, bvv, n1, 1);
    x[lane] = (lane < 32) ? v[0] : 0.f;
    {
        float acc = 0.f;
        if (lane < 2) { for (int k = 0; k < 32; k++) acc += x[k] * Wm3[k * 2 + lane]; }
        v[0] = (lane < 2) ? acc : 0.f;
        bvv[0] = (lane < 2) ? bm3[lane] : 0.f;
    }
    hyper_head_w<1>(v, bvv, n2, 0);
    if (lane < 2) out[(size_t)row * 2 + lane] = v[0];
}

// ---- launch ----
extern "C" void kernel_launch(void* const* d_in, const int* in_sizes, int n_in,
                              void* d_out, int out_size, void* d_ws, size_t ws_size,
                              hipStream_t stream) {
    const float* dch = (const float*)d_in[0];
    const float* dpc = (const float*)d_in[1];
    const float* dmc = (const float*)d_in[2];
    const float* dec = (const float*)d_in[3];
    const float* tes = (const float*)d_in[4];
    const float* tpc = (const float*)d_in[5];
    const float* tme = (const float*)d_in[6];
    const float* Wd1 = (const float*)d_in[7];  const float* bd1 = (const float*)d_in[8];
    const float* Wd2 = (const float*)d_in[9];  const float* bd2 = (const float*)d_in[10];
    const float* Wd3 = (const float*)d_in[11]; const float* bd3 = (const float*)d_in[12];
    const float* Wt1 = (const float*)d_in[13]; const float* bt1 = (const float*)d_in[14];
    const float* Wt2 = (const float*)d_in[15]; const float* bt2 = (const float*)d_in[16];
    const float* Wt3 = (const float*)d_in[17]; const float* bt3 = (const float*)d_in[18];
    const float* Wm1 = (const float*)d_in[19]; const float* bm1 = (const float*)d_in[20];
    const float* Wm2 = (const float*)d_in[21]; const float* bm2 = (const float*)d_in[22];
    const float* Wm3 = (const float*)d_in[23]; const float* bm3 = (const float*)d_in[24];

    const int B = in_sizes[0] / 768;   // 16384

    float* mx  = (float*)d_ws;                          // B*1024 f32
    short* xb  = (short*)(mx + (size_t)B * 1024);       // B*3456 bf16 (shared both branches)
    float* hf_d = (float*)(xb + (size_t)B * 3456);      // B*256 f32
    float* hf_t = hf_d + (size_t)B * 256;
    float* xn_d = hf_t + (size_t)B * 256;
    float* xn_t = xn_d + B;
    // packed weights: [ntile][KB][2][4096] shorts
    short* wp_d1 = (short*)(xn_t + B);                  // 8*54*8192
    short* wp_d2 = wp_d1 + 8 * 54 * 8192;               // 4*32*8192
    short* wp_d3 = wp_d2 + 4 * 32 * 8192;               // 2*16*8192
    short* wp_t1 = wp_d3 + 2 * 16 * 8192;
    short* wp_t2 = wp_t1 + 8 * 54 * 8192;
    short* wp_t3 = wp_t2 + 4 * 32 * 8192;

    dim3 blk(256);
    // fused pack: 2*(13824+4096+1024) = 37888 blocks
    hipLaunchKernelGGL(pack_all_kernel, dim3(37888), blk, 0, stream,
                       Wd1, wp_d1, Wd2, wp_d2, Wd3, wp_d3,
                       Wt1, wp_t1, Wt2, wp_t2, Wt3, wp_t3);

    // ---- drug branch ----
    hipLaunchKernelGGL(prep_kernel, dim3(B / 4), blk, 0, stream,
                       dch, dpc, dmc, dec, 768, 11, 167, 765, xb, xn_d);
    hipLaunchKernelGGL(gemm_mfma, dim3(8 * (B / 128)), blk, 0, stream, xb, 3456, 54, wp_d1, mx, 1024, 3);
    hipLaunchKernelGGL((epi_kernel<4>), dim3(B / 4), blk, 0, stream, mx, 1024, bd1, xn_d, xb, 2048, (float*)nullptr, 1);
    hipLaunchKernelGGL(gemm_mfma, dim3(4 * (B / 128)), blk, 0, stream, xb, 2048, 32, wp_d2, mx, 512, 2);
    hipLaunchKernelGGL((epi_kernel<2>), dim3(B / 4), blk, 0, stream, mx, 512, bd2, xn_d, xb, 1024, (float*)nullptr, 1);
    hipLaunchKernelGGL(gemm_mfma, dim3(2 * (B / 128)), blk, 0, stream, xb, 1024, 16, wp_d3, mx, 256, 1);
    hipLaunchKernelGGL((epi_kernel<1>), dim3(B / 4), blk, 0, stream, mx, 256, bd3, xn_d, (short*)nullptr, 0, hf_d, 0);

    // ---- target branch (reuses xb, mx) ----
    hipLaunchKernelGGL(prep_kernel, dim3(B / 4), blk, 0, stream,
                       tes, tpc, tme, (const float*)nullptr, 1280, 11, 420, 0, xb, xn_t);
    hipLaunchKernelGGL(gemm_mfma, dim3(8 * (B / 128)), blk, 0, stream, xb, 3456, 54, wp_t1, mx, 1024, 3);
    hipLaunchKernelGGL((epi_kernel<4>), dim3(B / 4), blk, 0, stream, mx, 1024, bt1, xn_t, xb, 2048, (float*)nullptr, 1);
    hipLaunchKernelGGL(gemm_mfma, dim3(4 * (B / 128)), blk, 0, stream, xb, 2048, 32, wp_t2, mx, 512, 2);
    hipLaunchKernelGGL((epi_kernel<2>), dim3(B / 4), blk, 0, stream, mx, 512, bt2, xn_t, xb, 1024, (float*)nullptr, 1);
    hipLaunchKernelGGL(gemm_mfma, dim3(2 * (B / 128)), blk, 0, stream, xb, 1024, 16, wp_t3, mx, 256, 1);
    hipLaunchKernelGGL((epi_kernel<1>), dim3(B / 4), blk, 0, stream, mx, 256, bt3, xn_t, (short*)nullptr, 0, hf_t, 0);

    // ---- merge + MLP -> out ----
    hipLaunchKernelGGL(merge_mlp_kernel, dim3(B / 4), blk, 0, stream,
                       hf_d, hf_t, xn_d, xn_t, Wm1, bm1, Wm2, bm2, Wm3, bm3, (float*)d_out);
}